// Round 9
// baseline (698.382 us; speedup 1.0000x reference)
//
#include <hip/hip_runtime.h>
#include <hip/hip_bf16.h>
#include <math.h>

#define B_   4
#define H_   8
#define NQ_  2048
#define NK_  2048
#define DM_  512
#define DK_  64
#define WL_  262144   // 512*512

typedef short  bf16x8 __attribute__((ext_vector_type(8)));
typedef float  f32x4  __attribute__((ext_vector_type(4)));

static __device__ __forceinline__ f32x4 MFMA16(bf16x8 a, bf16x8 b, f32x4 c) {
    return __builtin_amdgcn_mfma_f32_16x16x32_bf16(a, b, c, 0, 0, 0);
}
static __device__ __forceinline__ unsigned short f2bf(float f) {
    __hip_bfloat16 h = __float2bfloat16(f);
    unsigned short u; __builtin_memcpy(&u, &h, 2); return u;
}
static __device__ __forceinline__ float bf2f(unsigned short u) {
    unsigned int x = ((unsigned int)u) << 16;
    float f; __builtin_memcpy(&f, &x, 4); return f;
}
static __device__ __forceinline__ void glds16(const void* g, void* l) {
    __builtin_amdgcn_global_load_lds(
        (__attribute__((address_space(1))) const void*)g,
        (__attribute__((address_space(3))) void*)l, 16, 0, 0);
}
static __device__ __forceinline__ unsigned short q16(float w) {
    float t = w * 65536.f + 0.5f;
    t = fminf(t, 65535.f);
    return (unsigned short)(unsigned int)t;
}

// ---------------------------------------------------------------------------
// prep: fused W->u16 retile + mask->bits. Grid (qblk=32, bh=32), 256 thr.
// Block owns [bh][q0:q0+64][0:2048]: reads W rows CONTIGUOUSLY (8KB/row),
// writes u16 tiles [bh*32+qblk][kti][wv][16x64 swizzled] (256KB contiguous),
// and bitmask rows. Thread t handles cols 8t..8t+7 of each row.
// Swizzle: granule gg (4 u16) of subrow sr stored at position gg^sr.
// ---------------------------------------------------------------------------
__global__ __launch_bounds__(256) void prep(const unsigned char* __restrict__ Mk,
                                            const float* __restrict__ Wt,
                                            unsigned short* __restrict__ Wq,
                                            unsigned long long* __restrict__ bits)
{
    __shared__ int s_flag;
    const int tid = threadIdx.x;
    if (tid == 0) s_flag = 0;
    __syncthreads();
    {
        bool any = false;
#pragma unroll
        for (int i = 1; i < 16; i += 4)
            if (Mk[tid*16 + i]) any = true;
        if (any) s_flag = 1;
    }
    __syncthreads();
    const bool mByte = (s_flag != 0);

    const int qblk = blockIdx.x, bh = blockIdx.y;
    const size_t rowbase = (size_t)bh*NQ_ + qblk*64;
    unsigned short* wdst = Wq + (((size_t)bh*32 + qblk)*32)*4096;

    const int c0  = tid * 8;          // first col this thread handles
    const int kti = tid >> 3;         // c0/64
    const int gg0 = (c0 & 63) >> 2;   // granule within 64-col tile (2 granules)
    const int sh  = (tid & 7) * 8;    // bit shift within u64 word

    for (int r = 0; r < 64; ++r) {
        const int wv = r >> 4, sr = r & 15;
        const float* wrow = Wt + (rowbase + r)*NK_;
        const float4 a = *(const float4*)(wrow + c0);
        const float4 b = *(const float4*)(wrow + c0 + 4);
        ushort4 ua, ub;
        ua.x = q16(a.x); ua.y = q16(a.y); ua.z = q16(a.z); ua.w = q16(a.w);
        ub.x = q16(b.x); ub.y = q16(b.y); ub.z = q16(b.z); ub.w = q16(b.w);
        unsigned short* tile = wdst + ((size_t)kti*4 + wv)*1024;
        *(ushort4*)(tile + sr*64 + (((gg0    ) ^ sr) << 2)) = ua;
        *(ushort4*)(tile + sr*64 + (((gg0 + 1) ^ sr) << 2)) = ub;

        unsigned int nib8 = 0;
        if (mByte) {
            const unsigned long long mm =
                *(const unsigned long long*)(Mk + (rowbase + r)*NK_ + c0);
#pragma unroll
            for (int j = 0; j < 8; ++j)
                if ((mm >> (8*j)) & 0xffull) nib8 |= 1u << j;
        } else {
            const unsigned int* mrow = (const unsigned int*)Mk + (rowbase + r)*NK_ + c0;
            const uint4 m0 = *(const uint4*)mrow;
            const uint4 m1 = *(const uint4*)(mrow + 4);
            nib8 = (m0.x?1u:0u) | (m0.y?2u:0u) | (m0.z?4u:0u) | (m0.w?8u:0u) |
                   (m1.x?16u:0u) | (m1.y?32u:0u) | (m1.z?64u:0u) | (m1.w?128u:0u);
        }
        unsigned long long v = (unsigned long long)nib8 << sh;
        v |= __shfl_xor(v, 1, 64);
        v |= __shfl_xor(v, 2, 64);
        v |= __shfl_xor(v, 4, 64);
        if ((tid & 7) == 0)
            bits[(rowbase + r)*(NK_/64) + kti] = v;
    }
}

// ---------------------------------------------------------------------------
// W (512x512 fp32, [k][n]) -> WT_hi/WT_lo (bf16, [n][k]) for all 4 weights
// ---------------------------------------------------------------------------
__global__ __launch_bounds__(256) void wprep(const float* __restrict__ Wq,
                                             const float* __restrict__ Wk,
                                             const float* __restrict__ Wv,
                                             const float* __restrict__ Wo,
                                             unsigned short* __restrict__ out)
{
    __shared__ float tile[64][65];
    const int tid = threadIdx.x;
    const int k0 = blockIdx.x * 64, n0 = blockIdx.y * 64, w = blockIdx.z;
    const float* W = (w == 0) ? Wq : (w == 1) ? Wk : (w == 2) ? Wv : Wo;
    unsigned short* WTh = out + (size_t)w * 2 * WL_;
    unsigned short* WTl = WTh + WL_;

#pragma unroll
    for (int rd = 0; rd < 4; ++rd) {
        const int k = (tid >> 4) + 16*rd, c4 = (tid & 15) * 4;
        const float4 v4 = *(const float4*)(W + (size_t)(k0 + k)*DM_ + n0 + c4);
        tile[k][c4+0] = v4.x; tile[k][c4+1] = v4.y;
        tile[k][c4+2] = v4.z; tile[k][c4+3] = v4.w;
    }
    __syncthreads();
#pragma unroll
    for (int rd = 0; rd < 4; ++rd) {
        const int n = (tid >> 4) + 16*rd, kk = (tid & 15) * 4;
        unsigned short hh[4], ll[4];
#pragma unroll
        for (int j = 0; j < 4; ++j) {
            const float f = tile[kk + j][n];
            hh[j] = f2bf(f);
            ll[j] = f2bf(f - bf2f(hh[j]));
        }
        *(ushort4*)(WTh + (size_t)(n0 + n)*DM_ + k0 + kk) = make_ushort4(hh[0],hh[1],hh[2],hh[3]);
        *(ushort4*)(WTl + (size_t)(n0 + n)*DM_ + k0 + kk) = make_ushort4(ll[0],ll[1],ll[2],ll[3]);
    }
}

// ---------------------------------------------------------------------------
// Split-bf16 MFMA GEMM: C = A(fp32) @ W + bias (x oscale).
// MODE 0/1: 2-term (Ah*Wh + Ah*Wl) -> bf16 out.  MODE 2: 3-term -> fp32 out.
// ---------------------------------------------------------------------------
template<int MODE>
__global__ __launch_bounds__(256) void gemm_split(
    const float* __restrict__ A,
    const unsigned short* __restrict__ WTh,
    const unsigned short* __restrict__ WTl,
    const float* __restrict__ bias,
    void* __restrict__ outv, const float oscale)
{
    __shared__ unsigned short Ah[64][64], Al[64][64], Bh[64][64], Bl[64][64];

    const int tid = threadIdx.x;
    const int w = tid >> 6, lane = tid & 63, g = lane >> 4, r = lane & 15;
    const int m0 = blockIdx.x * 64, n0 = blockIdx.y * 64;

    char* pAh = (char*)&Ah[0][0];
    char* pAl = (char*)&Al[0][0];
    char* pBh = (char*)&Bh[0][0];
    char* pBl = (char*)&Bl[0][0];

    const f32x4 z4 = {0.f, 0.f, 0.f, 0.f};
    f32x4 acc[4] = {z4, z4, z4, z4};

    for (int kt = 0; kt < DM_; kt += 64) {
#pragma unroll
        for (int rd = 0; rd < 4; ++rd) {
            const int row = (tid >> 4) + 16*rd;
            const int c4  = (tid & 15) * 4;
            const float4 a4 = *(const float4*)(A + (size_t)(m0 + row)*DM_ + kt + c4);
            const float av[4] = {a4.x, a4.y, a4.z, a4.w};
            unsigned short hh[4];
#pragma unroll
            for (int j = 0; j < 4; ++j) hh[j] = f2bf(av[j]);
            const int bo = (c4 * 2) ^ ((row & 7) << 4);
            *(ushort4*)(pAh + row*128 + bo) = make_ushort4(hh[0],hh[1],hh[2],hh[3]);
            if (MODE == 2) {
                unsigned short ll[4];
#pragma unroll
                for (int j = 0; j < 4; ++j) ll[j] = f2bf(av[j] - bf2f(hh[j]));
                *(ushort4*)(pAl + row*128 + bo) = make_ushort4(ll[0],ll[1],ll[2],ll[3]);
            }
        }
#pragma unroll
        for (int rd = 0; rd < 2; ++rd) {
            const int idx = tid + 256*rd;
            const int row = idx >> 3;
            const int cb  = (idx & 7) * 16;
            const int bo  = cb ^ ((row & 7) << 4);
            const size_t goff = (size_t)(n0 + row)*DM_ + kt + (cb >> 1);
            *(bf16x8*)(pBh + row*128 + bo) = *(const bf16x8*)(WTh + goff);
            *(bf16x8*)(pBl + row*128 + bo) = *(const bf16x8*)(WTl + goff);
        }
        __syncthreads();

        const int swr = (r & 7) << 4;
#pragma unroll
        for (int ks = 0; ks < 2; ++ks) {
            const int xo = (64*ks + 16*g) ^ swr;
            const bf16x8 xh = *(const bf16x8*)(pAh + (16*w + r)*128 + xo);
#pragma unroll
            for (int nt = 0; nt < 4; ++nt) {
                const bf16x8 bh = *(const bf16x8*)(pBh + (16*nt + r)*128 + xo);
                const bf16x8 bl = *(const bf16x8*)(pBl + (16*nt + r)*128 + xo);
                if (MODE == 1) {
                    acc[nt] = MFMA16(xh, bh, acc[nt]);
                    acc[nt] = MFMA16(xh, bl, acc[nt]);
                } else if (MODE == 0) {
                    acc[nt] = MFMA16(bh, xh, acc[nt]);
                    acc[nt] = MFMA16(bl, xh, acc[nt]);
                } else {
                    const bf16x8 xl = *(const bf16x8*)(pAl + (16*w + r)*128 + xo);
                    acc[nt] = MFMA16(bh, xh, acc[nt]);
                    acc[nt] = MFMA16(bh, xl, acc[nt]);
                    acc[nt] = MFMA16(bl, xh, acc[nt]);
                }
            }
        }
        __syncthreads();
    }

    if (MODE == 0) {
        const int m = m0 + 16*w + r;
        const int b = m >> 11, q = m & 2047, h = blockIdx.y;
        unsigned short* dst = (unsigned short*)outv + (((size_t)(b*H_ + h))*NQ_ + q)*DK_;
#pragma unroll
        for (int nt = 0; nt < 4; ++nt) {
            unsigned short u[4];
#pragma unroll
            for (int j = 0; j < 4; ++j)
                u[j] = f2bf((acc[nt][j] + bias[n0 + 16*nt + 4*g + j]) * oscale);
            *(ushort4*)(dst + 16*nt + 4*g) = make_ushort4(u[0],u[1],u[2],u[3]);
        }
    } else if (MODE == 1) {
        const int b = m0 >> 11, h = blockIdx.y;
        const int key = (m0 & 2047) + 16*w + 4*g;
#pragma unroll
        for (int nt = 0; nt < 4; ++nt) {
            const int dv = 16*nt + r;
            const float bv = bias[n0 + dv];
            unsigned short u[4];
#pragma unroll
            for (int j = 0; j < 4; ++j) u[j] = f2bf(acc[nt][j] + bv);
            *(ushort4*)((unsigned short*)outv +
                        (((size_t)(b*H_ + h))*DK_ + dv)*NK_ + key) = make_ushort4(u[0],u[1],u[2],u[3]);
        }
    } else {
        const int m = m0 + 16*w + r;
        float* dst = (float*)outv + (size_t)m*DM_ + n0;
#pragma unroll
        for (int nt = 0; nt < 4; ++nt) {
            float4 o4;
            o4.x = acc[nt][0] + bias[n0 + 16*nt + 4*g + 0];
            o4.y = acc[nt][1] + bias[n0 + 16*nt + 4*g + 1];
            o4.z = acc[nt][2] + bias[n0 + 16*nt + 4*g + 2];
            o4.w = acc[nt][3] + bias[n0 + 16*nt + 4*g + 3];
            *(float4*)(dst + 16*nt + 4*g) = o4;
        }
    }
}

// ---------------------------------------------------------------------------
// MFMA flash attention. 4 waves = 4 q-subblocks of 16 rows; K-step 64.
// W now u16 fixed-point in prep's tiled layout: per iter per wave one
// CONTIGUOUS 2KB chunk staged via 2 glds16 (sequential DRAM stream).
// 2^-16 dequant folded into Q projection scale.
// ---------------------------------------------------------------------------
__global__ __launch_bounds__(256) void attn_mfma(
    const unsigned short* __restrict__ Qb,
    const unsigned short* __restrict__ Kb,
    const unsigned short* __restrict__ Vt,
    const unsigned short* __restrict__ Wq16,
    const unsigned long long* __restrict__ Mb,
    float* __restrict__ O)
{
    __shared__ unsigned short Wlds[2][4][1024];  // [buf][wave][16x64 u16 swizzled]
    __shared__ short Pl[4][1024];                // P bounce, 2KB/wave

    const int tid  = threadIdx.x;
    const int wv   = tid >> 6, lane = tid & 63;
    const int g    = lane >> 4, r = lane & 15;
    const int q0   = blockIdx.x * 64 + wv * 16;
    const int bh   = blockIdx.y;

    const size_t kvBase = (size_t)bh * NK_ * DK_;
    const unsigned short* qp = Qb + kvBase + (size_t)(q0 + r)*DK_ + 8*g;
    const bf16x8 qf0 = *(const bf16x8*)qp;
    const bf16x8 qf1 = *(const bf16x8*)(qp + 32);

    const unsigned short* wq_base = Wq16 + (((size_t)bh*32 + blockIdx.x)*32)*4096;
    const unsigned long long* brow = Mb + ((size_t)bh*NQ_ + q0 + r)*(NK_/64);
    const unsigned short* kbase = Kb + kvBase + (size_t)r*DK_ + 8*g;
    const unsigned short* vbase = Vt + kvBase + (size_t)r*NK_ + 8*g;

    const f32x4 zero4 = {0.f, 0.f, 0.f, 0.f};
    f32x4 oa0 = zero4, oa1 = zero4, oa2 = zero4, oa3 = zero4;
    float m_run = -1e30f, l_run = 0.f;

    char* pbase = (char*)&Pl[wv][0];
    const int roff = r * 128;
    const int sw   = (r & 7) << 4;

    auto stage = [&](int buf, int kti) {
        const unsigned short* src = wq_base + ((size_t)kti*4 + wv)*1024;
        unsigned short* dst = &Wlds[buf][wv][0];
        glds16(src + (lane << 3),       dst + (lane << 3));
        glds16(src + 512 + (lane << 3), dst + 512 + (lane << 3));
    };

    bf16x8 k00,k01,k10,k11,k20,k21,k30,k31;           // single-buffered K
    bf16x8 v00,v01,v02,v03, v10,v11,v12,v13;          // single-buffered V

#define LOADK(ktv) do { \
    const unsigned short* kp_ = kbase + (size_t)(ktv)*DK_;      \
    k00 = *(const bf16x8*)kp_;         k01 = *(const bf16x8*)(kp_ + 32);          \
    k10 = *(const bf16x8*)(kp_+1024);  k11 = *(const bf16x8*)(kp_ + 1024 + 32);   \
    k20 = *(const bf16x8*)(kp_+2048);  k21 = *(const bf16x8*)(kp_ + 2048 + 32);   \
    k30 = *(const bf16x8*)(kp_+3072);  k31 = *(const bf16x8*)(kp_ + 3072 + 32);   \
} while (0)

#define LOADV(ktv) do { \
    const unsigned short* vp_ = vbase + (ktv);                  \
    v00 = *(const bf16x8*)(vp_);             v01 = *(const bf16x8*)(vp_ + 16*NK_);      \
    v02 = *(const bf16x8*)(vp_ + 32*NK_);    v03 = *(const bf16x8*)(vp_ + 48*NK_);      \
    v10 = *(const bf16x8*)(vp_ + 32);        v11 = *(const bf16x8*)(vp_ + 16*NK_ + 32); \
    v12 = *(const bf16x8*)(vp_ + 32*NK_+32); v13 = *(const bf16x8*)(vp_ + 48*NK_ + 32); \
} while (0)

    // ---- prologue ----
    stage(0, 0);
    unsigned long long bcur = brow[0];
    LOADK(0);
    LOADV(0);
    __builtin_amdgcn_sched_barrier(0);

#pragma unroll 1
    for (int i = 0; i < 32; ++i) {
        const int kt  = i * 64;
        const int p   = i & 1;
        const int ktn = (kt + 64 < NK_) ? kt + 64 : kt;

        // ---- QK MFMA ----
        f32x4 sa0 = zero4, sa1 = zero4, sa2 = zero4, sa3 = zero4;
        __builtin_amdgcn_s_setprio(1);
        sa0 = MFMA16(k00, qf0, sa0); sa0 = MFMA16(k01, qf1, sa0);
        sa1 = MFMA16(k10, qf0, sa1); sa1 = MFMA16(k11, qf1, sa1);
        sa2 = MFMA16(k20, qf0, sa2); sa2 = MFMA16(k21, qf1, sa2);
        sa3 = MFMA16(k30, qf0, sa3); sa3 = MFMA16(k31, qf1, sa3);
        __builtin_amdgcn_s_setprio(0);
        __builtin_amdgcn_sched_barrier(0);

        // ---- W fragments from swizzled LDS (u16) ----
        const unsigned short* wb = &Wlds[p][wv][0];
        ushort4 wu[4];
#pragma unroll
        for (int t = 0; t < 4; ++t)
            wu[t] = *(const ushort4*)(wb + r*64 + (((4*t + g) ^ r) << 2));

        // ---- logits = maskbit ? -1e30 : s * w  (2^-16 folded into Q) ----
        float lg[16];
        const f32x4 sav[4] = {sa0, sa1, sa2, sa3};
#pragma unroll
        for (int t = 0; t < 4; ++t) {
            const unsigned int half = (t & 2) ? (unsigned int)(bcur >> 32)
                                              : (unsigned int)bcur;
            const float wv4[4] = {(float)wu[t].x, (float)wu[t].y,
                                  (float)wu[t].z, (float)wu[t].w};
#pragma unroll
            for (int j = 0; j < 4; ++j) {
                const unsigned int bit = (half >> (16*(t & 1) + 4*g + j)) & 1u;
                lg[4*t+j] = bit ? -1e30f : sav[t][j] * wv4[j];
            }
        }

        // ---- online softmax ----
        float mx = lg[0];
#pragma unroll
        for (int i2 = 1; i2 < 16; ++i2) mx = fmaxf(mx, lg[i2]);
        mx = fmaxf(mx, __shfl_xor(mx, 16, 64));
        mx = fmaxf(mx, __shfl_xor(mx, 32, 64));
        const float mnew = fmaxf(m_run, mx);
        const float fsc  = __expf(m_run - mnew);
        m_run = mnew;
        float p16[16], rs = 0.f;
#pragma unroll
        for (int i2 = 0; i2 < 16; ++i2) { p16[i2] = __expf(lg[i2] - mnew); rs += p16[i2]; }
        rs += __shfl_xor(rs, 16, 64);
        rs += __shfl_xor(rs, 32, 64);
        l_run = l_run * fsc + rs;
        __builtin_amdgcn_sched_barrier(0);

        // ---- issue next-iter prefetches (stage, bits, K overwrite) ----
        stage(p ^ 1, ktn >> 6);
        const unsigned long long bnxt = brow[ktn >> 6];
        LOADK(ktn);
        __builtin_amdgcn_sched_barrier(0);

        // ---- pack P -> wave-private swizzled LDS ----
#pragma unroll
        for (int t = 0; t < 4; ++t) {
            const unsigned int w0 = (unsigned int)f2bf(p16[4*t+0]) |
                                    ((unsigned int)f2bf(p16[4*t+1]) << 16);
            const unsigned int w1 = (unsigned int)f2bf(p16[4*t+2]) |
                                    ((unsigned int)f2bf(p16[4*t+3]) << 16);
            *(int2*)(pbase + roff + ((32*t + 8*g) ^ sw)) = make_int2((int)w0, (int)w1);
        }
        asm volatile("s_waitcnt lgkmcnt(0)" ::: "memory");
        __builtin_amdgcn_sched_barrier(0);
        const bf16x8 pa0 = *(const bf16x8*)(pbase + roff + ((     16*g) ^ sw));
        const bf16x8 pa1 = *(const bf16x8*)(pbase + roff + ((64 + 16*g) ^ sw));

        // ---- rescale O ----
        float fr[4];
#pragma unroll
        for (int j = 0; j < 4; ++j) fr[j] = __shfl(fsc, 4*g + j, 64);
#pragma unroll
        for (int j = 0; j < 4; ++j) {
            oa0[j] *= fr[j]; oa1[j] *= fr[j]; oa2[j] *= fr[j]; oa3[j] *= fr[j];
        }

        // ---- O += P.V ----
        __builtin_amdgcn_s_setprio(1);
        oa0 = MFMA16(pa0, v00, oa0); oa1 = MFMA16(pa0, v01, oa1);
        oa2 = MFMA16(pa0, v02, oa2); oa3 = MFMA16(pa0, v03, oa3);
        oa0 = MFMA16(pa1, v10, oa0); oa1 = MFMA16(pa1, v11, oa1);
        oa2 = MFMA16(pa1, v12, oa2); oa3 = MFMA16(pa1, v13, oa3);
        __builtin_amdgcn_s_setprio(0);
        __builtin_amdgcn_sched_barrier(0);

        // ---- issue next-iter V ----
        LOADV(ktn);
        __builtin_amdgcn_sched_barrier(0);
        bcur = bnxt;
    }
#undef LOADK
#undef LOADV

    // ---- epilogue: normalize + write (b, q, h*64+dv) fp32 ----
    const float inv = 1.0f / l_run;
    float ir[4];
#pragma unroll
    for (int j = 0; j < 4; ++j) ir[j] = __shfl(inv, 4*g + j, 64);
    const int bb = bh >> 3, h = bh & 7;
    const f32x4 oav[4] = {oa0, oa1, oa2, oa3};
#pragma unroll
    for (int nt = 0; nt < 4; ++nt)
#pragma unroll
        for (int j = 0; j < 4; ++j)
            O[((size_t)(bb*NQ_ + q0 + 4*g + j))*DM_ + h*64 + 16*nt + r] = oav[nt][j] * ir[j];
}

// ---------------------------------------------------------------------------
extern "C" void kernel_launch(void* const* d_in, const int* in_sizes, int n_in,
                              void* d_out, int out_size, void* d_ws, size_t ws_size,
                              hipStream_t stream) {
    (void)in_sizes; (void)n_in; (void)out_size; (void)ws_size;

    const float* q    = (const float*)d_in[0];
    const float* k    = (const float*)d_in[1];
    const float* v    = (const float*)d_in[2];
    const float* attw = (const float*)d_in[3];
    const unsigned char* mask = (const unsigned char*)d_in[4];
    const float* Wq = (const float*)d_in[5];
    const float* bq = (const float*)d_in[6];
    const float* Wk = (const float*)d_in[7];
    const float* bk = (const float*)d_in[8];
    const float* Wv = (const float*)d_in[9];
    const float* bv = (const float*)d_in[10];
    const float* Wo = (const float*)d_in[11];
    const float* bo = (const float*)d_in[12];
    float* out = (float*)d_out;

    // ws (shorts): q_bf[NE] k_bf[NE] vT[NE] wt[8*WL] | bits[2Mi u64]
    //              | wq16[128Mi u16] | o_ws fp32
    const long long NE = (long long)B_*H_*NQ_*DK_;        // 4Mi
    unsigned short* q_bf = (unsigned short*)d_ws;
    unsigned short* k_bf = q_bf + NE;
    unsigned short* vT   = q_bf + 2*NE;
    unsigned short* wt   = q_bf + 3*NE;
    unsigned long long* bits = (unsigned long long*)(wt + 8LL*WL_);
    const long long NB = (long long)B_*H_*NQ_*NK_/64;     // 2Mi
    unsigned short* wq16 = (unsigned short*)(bits + NB);
    float* o_ws = (float*)(wq16 + 1024LL*32*4096);

    const dim3 blk(256);
    wprep<<<dim3(8, 8, 4), blk, 0, stream>>>(Wq, Wk, Wv, Wo, wt);
    prep<<<dim3(32, 32), blk, 0, stream>>>(mask, attw, wq16, bits);

    const dim3 gg(128, 8);
    // Q projection: fold attention scale 0.125 AND u16 dequant 2^-16
    gemm_split<0><<<gg, blk, 0, stream>>>(q, wt + 0*WL_, wt + 1*WL_, bq, q_bf,
                                          0.125f / 65536.f);
    gemm_split<0><<<gg, blk, 0, stream>>>(k, wt + 2*WL_, wt + 3*WL_, bk, k_bf, 1.0f);
    gemm_split<1><<<gg, blk, 0, stream>>>(v, wt + 4*WL_, wt + 5*WL_, bv, vT, 1.0f);

    attn_mfma<<<dim3(NQ_/64, B_*H_), blk, 0, stream>>>(q_bf, k_bf, vT, wq16, bits, o_ws);

    gemm_split<2><<<gg, blk, 0, stream>>>(o_ws, wt + 6*WL_, wt + 7*WL_, bo, out, 1.0f);
}

// Round 10
// 545.282 us; speedup vs baseline: 1.2808x; 1.2808x over previous
//
#include <hip/hip_runtime.h>
#include <hip/hip_bf16.h>
#include <math.h>

#define B_   4
#define H_   8
#define NQ_  2048
#define NK_  2048
#define DM_  512
#define DK_  64
#define WL_  262144   // 512*512

typedef short  bf16x8 __attribute__((ext_vector_type(8)));
typedef float  f32x4  __attribute__((ext_vector_type(4)));
typedef __attribute__((address_space(3))) float lds_f;

static __device__ __forceinline__ f32x4 MFMA16(bf16x8 a, bf16x8 b, f32x4 c) {
    return __builtin_amdgcn_mfma_f32_16x16x32_bf16(a, b, c, 0, 0, 0);
}
static __device__ __forceinline__ unsigned short f2bf(float f) {
    __hip_bfloat16 h = __float2bfloat16(f);
    unsigned short u; __builtin_memcpy(&u, &h, 2); return u;
}
static __device__ __forceinline__ float bf2f(unsigned short u) {
    unsigned int x = ((unsigned int)u) << 16;
    float f; __builtin_memcpy(&f, &x, 4); return f;
}
static __device__ __forceinline__ void glds16(const void* g, void* l) {
    __builtin_amdgcn_global_load_lds(
        (__attribute__((address_space(1))) const void*)g,
        (__attribute__((address_space(3))) void*)l, 16, 0, 0);
}

// ---------------------------------------------------------------------------
// mask -> bitmask, coalesced (lane-contiguous uint4 loads, grid-stride)
// ---------------------------------------------------------------------------
__global__ __launch_bounds__(256) void conv_mask(const unsigned char* __restrict__ Mk,
                                                 unsigned long long* __restrict__ bits)
{
    __shared__ int s_flag;
    const int tid = threadIdx.x;
    if (tid == 0) s_flag = 0;
    __syncthreads();
    {
        bool any = false;
#pragma unroll
        for (int i = 1; i < 16; i += 4)
            if (Mk[tid*16 + i]) any = true;
        if (any) s_flag = 1;
    }
    __syncthreads();

    const long long NELEM = (long long)B_*H_*NQ_*NK_;      // 128Mi
    const long long nth   = (long long)gridDim.x * 256;
    const long long T     = (long long)blockIdx.x * 256 + tid;
    unsigned short* b16   = (unsigned short*)bits;
    const uint4*    src   = (const uint4*)Mk;

    if (s_flag) {
        const long long n = NELEM / 16;
        for (long long t = T; t < n; t += nth) {
            const uint4 u = src[t];
            const unsigned int w[4] = {u.x, u.y, u.z, u.w};
            unsigned int m = 0;
#pragma unroll
            for (int j = 0; j < 4; ++j)
#pragma unroll
                for (int b2 = 0; b2 < 4; ++b2)
                    if ((w[j] >> (8*b2)) & 0xffu) m |= 1u << (4*j + b2);
            b16[t] = (unsigned short)m;
        }
    } else {
        const long long n = NELEM / 4;
        const int l3 = tid & 3;
        for (long long t = T; t < n; t += nth) {
            const uint4 u = src[t];
            const unsigned int nib = (u.x ? 1u : 0u) | (u.y ? 2u : 0u) |
                                     (u.z ? 4u : 0u) | (u.w ? 8u : 0u);
            unsigned int v = nib << (4*l3);
            v |= __shfl_xor(v, 1, 64);
            v |= __shfl_xor(v, 2, 64);
            if (l3 == 0) b16[t >> 2] = (unsigned short)v;
        }
    }
}

// ---------------------------------------------------------------------------
// W (512x512 fp32, [k][n]) -> WT_hi/WT_lo (bf16, [n][k]) for all 4 weights
// ---------------------------------------------------------------------------
__global__ __launch_bounds__(256) void wprep(const float* __restrict__ Wq,
                                             const float* __restrict__ Wk,
                                             const float* __restrict__ Wv,
                                             const float* __restrict__ Wo,
                                             unsigned short* __restrict__ out)
{
    __shared__ float tile[64][65];
    const int tid = threadIdx.x;
    const int k0 = blockIdx.x * 64, n0 = blockIdx.y * 64, w = blockIdx.z;
    const float* W = (w == 0) ? Wq : (w == 1) ? Wk : (w == 2) ? Wv : Wo;
    unsigned short* WTh = out + (size_t)w * 2 * WL_;
    unsigned short* WTl = WTh + WL_;

#pragma unroll
    for (int rd = 0; rd < 4; ++rd) {
        const int k = (tid >> 4) + 16*rd, c4 = (tid & 15) * 4;
        const float4 v4 = *(const float4*)(W + (size_t)(k0 + k)*DM_ + n0 + c4);
        tile[k][c4+0] = v4.x; tile[k][c4+1] = v4.y;
        tile[k][c4+2] = v4.z; tile[k][c4+3] = v4.w;
    }
    __syncthreads();
#pragma unroll
    for (int rd = 0; rd < 4; ++rd) {
        const int n = (tid >> 4) + 16*rd, kk = (tid & 15) * 4;
        unsigned short hh[4], ll[4];
#pragma unroll
        for (int j = 0; j < 4; ++j) {
            const float f = tile[kk + j][n];
            hh[j] = f2bf(f);
            ll[j] = f2bf(f - bf2f(hh[j]));
        }
        *(ushort4*)(WTh + (size_t)(n0 + n)*DM_ + k0 + kk) = make_ushort4(hh[0],hh[1],hh[2],hh[3]);
        *(ushort4*)(WTl + (size_t)(n0 + n)*DM_ + k0 + kk) = make_ushort4(ll[0],ll[1],ll[2],ll[3]);
    }
}

// ---------------------------------------------------------------------------
// Split-bf16 MFMA GEMM: C = A(fp32) @ W + bias (x oscale).
// MODE 0/1: 2-term (Ah*Wh + Ah*Wl) -> bf16 out.  MODE 2: 3-term -> fp32 out.
// ---------------------------------------------------------------------------
template<int MODE>
__global__ __launch_bounds__(256) void gemm_split(
    const float* __restrict__ A,
    const unsigned short* __restrict__ WTh,
    const unsigned short* __restrict__ WTl,
    const float* __restrict__ bias,
    void* __restrict__ outv, const float oscale)
{
    __shared__ unsigned short Ah[64][64], Al[64][64], Bh[64][64], Bl[64][64];

    const int tid = threadIdx.x;
    const int w = tid >> 6, lane = tid & 63, g = lane >> 4, r = lane & 15;
    const int m0 = blockIdx.x * 64, n0 = blockIdx.y * 64;

    char* pAh = (char*)&Ah[0][0];
    char* pAl = (char*)&Al[0][0];
    char* pBh = (char*)&Bh[0][0];
    char* pBl = (char*)&Bl[0][0];

    const f32x4 z4 = {0.f, 0.f, 0.f, 0.f};
    f32x4 acc[4] = {z4, z4, z4, z4};

    for (int kt = 0; kt < DM_; kt += 64) {
#pragma unroll
        for (int rd = 0; rd < 4; ++rd) {
            const int row = (tid >> 4) + 16*rd;
            const int c4  = (tid & 15) * 4;
            const float4 a4 = *(const float4*)(A + (size_t)(m0 + row)*DM_ + kt + c4);
            const float av[4] = {a4.x, a4.y, a4.z, a4.w};
            unsigned short hh[4];
#pragma unroll
            for (int j = 0; j < 4; ++j) hh[j] = f2bf(av[j]);
            const int bo = (c4 * 2) ^ ((row & 7) << 4);
            *(ushort4*)(pAh + row*128 + bo) = make_ushort4(hh[0],hh[1],hh[2],hh[3]);
            if (MODE == 2) {
                unsigned short ll[4];
#pragma unroll
                for (int j = 0; j < 4; ++j) ll[j] = f2bf(av[j] - bf2f(hh[j]));
                *(ushort4*)(pAl + row*128 + bo) = make_ushort4(ll[0],ll[1],ll[2],ll[3]);
            }
        }
#pragma unroll
        for (int rd = 0; rd < 2; ++rd) {
            const int idx = tid + 256*rd;
            const int row = idx >> 3;
            const int cb  = (idx & 7) * 16;
            const int bo  = cb ^ ((row & 7) << 4);
            const size_t goff = (size_t)(n0 + row)*DM_ + kt + (cb >> 1);
            *(bf16x8*)(pBh + row*128 + bo) = *(const bf16x8*)(WTh + goff);
            *(bf16x8*)(pBl + row*128 + bo) = *(const bf16x8*)(WTl + goff);
        }
        __syncthreads();

        const int swr = (r & 7) << 4;
#pragma unroll
        for (int ks = 0; ks < 2; ++ks) {
            const int xo = (64*ks + 16*g) ^ swr;
            const bf16x8 xh = *(const bf16x8*)(pAh + (16*w + r)*128 + xo);
#pragma unroll
            for (int nt = 0; nt < 4; ++nt) {
                const bf16x8 bh = *(const bf16x8*)(pBh + (16*nt + r)*128 + xo);
                const bf16x8 bl = *(const bf16x8*)(pBl + (16*nt + r)*128 + xo);
                if (MODE == 1) {
                    acc[nt] = MFMA16(xh, bh, acc[nt]);
                    acc[nt] = MFMA16(xh, bl, acc[nt]);
                } else if (MODE == 0) {
                    acc[nt] = MFMA16(bh, xh, acc[nt]);
                    acc[nt] = MFMA16(bl, xh, acc[nt]);
                } else {
                    const bf16x8 xl = *(const bf16x8*)(pAl + (16*w + r)*128 + xo);
                    acc[nt] = MFMA16(bh, xh, acc[nt]);
                    acc[nt] = MFMA16(bh, xl, acc[nt]);
                    acc[nt] = MFMA16(bl, xh, acc[nt]);
                }
            }
        }
        __syncthreads();
    }

    if (MODE == 0) {
        const int m = m0 + 16*w + r;
        const int b = m >> 11, q = m & 2047, h = blockIdx.y;
        unsigned short* dst = (unsigned short*)outv + (((size_t)(b*H_ + h))*NQ_ + q)*DK_;
#pragma unroll
        for (int nt = 0; nt < 4; ++nt) {
            unsigned short u[4];
#pragma unroll
            for (int j = 0; j < 4; ++j)
                u[j] = f2bf((acc[nt][j] + bias[n0 + 16*nt + 4*g + j]) * oscale);
            *(ushort4*)(dst + 16*nt + 4*g) = make_ushort4(u[0],u[1],u[2],u[3]);
        }
    } else if (MODE == 1) {
        const int b = m0 >> 11, h = blockIdx.y;
        const int key = (m0 & 2047) + 16*w + 4*g;
#pragma unroll
        for (int nt = 0; nt < 4; ++nt) {
            const int dv = 16*nt + r;
            const float bv = bias[n0 + dv];
            unsigned short u[4];
#pragma unroll
            for (int j = 0; j < 4; ++j) u[j] = f2bf(acc[nt][j] + bv);
            *(ushort4*)((unsigned short*)outv +
                        (((size_t)(b*H_ + h))*DK_ + dv)*NK_ + key) = make_ushort4(u[0],u[1],u[2],u[3]);
        }
    } else {
        const int m = m0 + 16*w + r;
        float* dst = (float*)outv + (size_t)m*DM_ + n0;
#pragma unroll
        for (int nt = 0; nt < 4; ++nt) {
            float4 o4;
            o4.x = acc[nt][0] + bias[n0 + 16*nt + 4*g + 0];
            o4.y = acc[nt][1] + bias[n0 + 16*nt + 4*g + 1];
            o4.z = acc[nt][2] + bias[n0 + 16*nt + 4*g + 2];
            o4.w = acc[nt][3] + bias[n0 + 16*nt + 4*g + 3];
            *(float4*)(dst + 16*nt + 4*g) = o4;
        }
    }
}

// ---------------------------------------------------------------------------
// MFMA flash attention. 4 waves = 4 q-subblocks of 16 rows.
// W fp32 staged in 256-key super-tiles: 16 glds x 1KB contiguous row chunks
// per wave (DRAM page friendly), double-buffered, wave-private (no barriers).
// LDS rows padded to 1040B -> all W ds_reads 2-way-free (no swizzle).
// W fragments read via inline-asm ds_read_b128 with ONE counted vmcnt per
// super-tile (compiler's conservative vmcnt(0) bypassed).
// ---------------------------------------------------------------------------
__global__ __launch_bounds__(256) void attn_mfma(
    const unsigned short* __restrict__ Qb,
    const unsigned short* __restrict__ Kb,
    const unsigned short* __restrict__ Vt,
    const float* __restrict__ Wt,
    const unsigned long long* __restrict__ Mb,
    float* __restrict__ O)
{
    extern __shared__ float Wdyn[];      // 2 bufs x 64 rows x 260 floats (pad 4)
    __shared__ short Pl[4][1024];        // P bounce, 2KB/wave

    const int tid  = threadIdx.x;
    const int wv   = tid >> 6, lane = tid & 63;
    const int g    = lane >> 4, r = lane & 15;
    const int q0   = blockIdx.x * 64 + wv * 16;
    const int bh   = blockIdx.y;

    const size_t kvBase = (size_t)bh * NK_ * DK_;
    const unsigned short* qp = Qb + kvBase + (size_t)(q0 + r)*DK_ + 8*g;
    const bf16x8 qf0 = *(const bf16x8*)qp;
    const bf16x8 qf1 = *(const bf16x8*)(qp + 32);
    __builtin_amdgcn_sched_barrier(0);

    const float* wbase_g = Wt + ((size_t)bh*NQ_ + q0)*NK_;   // wave's 16 rows
    const unsigned long long* brow = Mb + ((size_t)bh*NQ_ + q0 + r)*(NK_/64);
    const unsigned short* kbase = Kb + kvBase + (size_t)r*DK_ + 8*g;
    const unsigned short* vbase = Vt + kvBase + (size_t)r*NK_ + 8*g;

    const f32x4 zero4 = {0.f, 0.f, 0.f, 0.f};
    f32x4 oa0 = zero4, oa1 = zero4, oa2 = zero4, oa3 = zero4;
    float m_run = -1e30f, l_run = 0.f;

    char* pbase = (char*)&Pl[wv][0];
    const int roff = r * 128;
    const int sw   = (r & 7) << 4;

    // stage super-tile si2 (cols [256*si2, 256*si2+256)) into buffer pbuf:
    // 16 glds, each one row's 1KB contiguous chunk. Wave-private rows.
    auto stage = [&](int pbuf, int si2) {
        float* dst = Wdyn + pbuf*16640 + (wv*16)*260 + lane*4;
        const float* src = wbase_g + si2*256 + lane*4;
#pragma unroll
        for (int rr = 0; rr < 16; ++rr)
            glds16(src + (size_t)rr*NK_, dst + rr*260);
    };

    bf16x8 k00,k01,k10,k11,k20,k21,k30,k31;
    bf16x8 v00,v01,v02,v03, v10,v11,v12,v13;

#define LOADK(ktv) do { \
    const unsigned short* kp_ = kbase + (size_t)(ktv)*DK_;      \
    k00 = *(const bf16x8*)kp_;         k01 = *(const bf16x8*)(kp_ + 32);          \
    k10 = *(const bf16x8*)(kp_+1024);  k11 = *(const bf16x8*)(kp_ + 1024 + 32);   \
    k20 = *(const bf16x8*)(kp_+2048);  k21 = *(const bf16x8*)(kp_ + 2048 + 32);   \
    k30 = *(const bf16x8*)(kp_+3072);  k31 = *(const bf16x8*)(kp_ + 3072 + 32);   \
} while (0)

#define LOADV(ktv) do { \
    const unsigned short* vp_ = vbase + (ktv);                  \
    v00 = *(const bf16x8*)(vp_);             v01 = *(const bf16x8*)(vp_ + 16*NK_);      \
    v02 = *(const bf16x8*)(vp_ + 32*NK_);    v03 = *(const bf16x8*)(vp_ + 48*NK_);      \
    v10 = *(const bf16x8*)(vp_ + 32);        v11 = *(const bf16x8*)(vp_ + 16*NK_ + 32); \
    v12 = *(const bf16x8*)(vp_ + 32*NK_+32); v13 = *(const bf16x8*)(vp_ + 48*NK_ + 32); \
} while (0)

    // ---- prologue: order pinned: [Q] [stage0] [bits+K+V] ----
    stage(0, 0);
    __builtin_amdgcn_sched_barrier(0);
    unsigned long long bcur = brow[0];
    LOADK(0);
    LOADV(0);
    __builtin_amdgcn_sched_barrier(0);

#pragma unroll 1
    for (int si = 0; si < 8; ++si) {
        const int p = si & 1;
#pragma unroll
        for (int s = 0; s < 4; ++s) {
            const int i    = si*4 + s;
            const int in_  = (i + 1 < 32) ? i + 1 : i;
            const int ktn  = in_ * 64;

            // ---- 1. QK MFMA (compiler's counted K-wait) ----
            f32x4 sa0 = zero4, sa1 = zero4, sa2 = zero4, sa3 = zero4;
            __builtin_amdgcn_s_setprio(1);
            sa0 = MFMA16(k00, qf0, sa0); sa0 = MFMA16(k01, qf1, sa0);
            sa1 = MFMA16(k10, qf0, sa1); sa1 = MFMA16(k11, qf1, sa1);
            sa2 = MFMA16(k20, qf0, sa2); sa2 = MFMA16(k21, qf1, sa2);
            sa3 = MFMA16(k30, qf0, sa3); sa3 = MFMA16(k31, qf1, sa3);
            __builtin_amdgcn_s_setprio(0);
            __builtin_amdgcn_sched_barrier(0);

            // ---- 2. stage next super-tile (2 sub-iters of cover) ----
            if (s == 2 && si < 7) {
                stage(p ^ 1, si + 1);
                __builtin_amdgcn_sched_barrier(0);
            }

            // ---- 3. W fragments: counted drain once per super-tile ----
            if (s == 0) {
                if (si == 0) asm volatile("s_waitcnt vmcnt(17)" ::: "memory");
                else         asm volatile("s_waitcnt vmcnt(34)" ::: "memory");
                __builtin_amdgcn_sched_barrier(0);
            }
            f32x4 wf[4];
            {
                lds_f* wrp = (lds_f*)(Wdyn + p*16640 + (wv*16 + r)*260 + 64*s) + 4*g;
#pragma unroll
                for (int t = 0; t < 4; ++t) {
                    lds_f* a = wrp + 16*t;
                    asm volatile("ds_read_b128 %0, %1" : "=v"(wf[t]) : "v"(a));
                }
            }
            asm volatile("s_waitcnt lgkmcnt(0)" ::: "memory");
            __builtin_amdgcn_sched_barrier(0);

            // ---- 4. logits + online softmax ----
            float lg[16];
            const f32x4 sav[4] = {sa0, sa1, sa2, sa3};
#pragma unroll
            for (int t = 0; t < 4; ++t) {
                const unsigned int half = (t & 2) ? (unsigned int)(bcur >> 32)
                                                  : (unsigned int)bcur;
#pragma unroll
                for (int j = 0; j < 4; ++j) {
                    const unsigned int bit = (half >> (16*(t & 1) + 4*g + j)) & 1u;
                    lg[4*t+j] = bit ? -1e30f : sav[t][j] * wf[t][j];
                }
            }
            float mx = lg[0];
#pragma unroll
            for (int i2 = 1; i2 < 16; ++i2) mx = fmaxf(mx, lg[i2]);
            mx = fmaxf(mx, __shfl_xor(mx, 16, 64));
            mx = fmaxf(mx, __shfl_xor(mx, 32, 64));
            const float mnew = fmaxf(m_run, mx);
            const float fsc  = __expf(m_run - mnew);
            m_run = mnew;
            float p16[16], rs = 0.f;
#pragma unroll
            for (int i2 = 0; i2 < 16; ++i2) { p16[i2] = __expf(lg[i2] - mnew); rs += p16[i2]; }
            rs += __shfl_xor(rs, 16, 64);
            rs += __shfl_xor(rs, 32, 64);
            l_run = l_run * fsc + rs;
            __builtin_amdgcn_sched_barrier(0);

            // ---- 5. K(next) + bits(next) ----
            LOADK(ktn);
            const unsigned long long bnxt = brow[in_];
            __builtin_amdgcn_sched_barrier(0);

            // ---- 6. P pack + O rescale ----
#pragma unroll
            for (int t = 0; t < 4; ++t) {
                const unsigned int w0 = (unsigned int)f2bf(p16[4*t+0]) |
                                        ((unsigned int)f2bf(p16[4*t+1]) << 16);
                const unsigned int w1 = (unsigned int)f2bf(p16[4*t+2]) |
                                        ((unsigned int)f2bf(p16[4*t+3]) << 16);
                *(int2*)(pbase + roff + ((32*t + 8*g) ^ sw)) = make_int2((int)w0, (int)w1);
            }
            asm volatile("s_waitcnt lgkmcnt(0)" ::: "memory");
            __builtin_amdgcn_sched_barrier(0);
            const bf16x8 pa0 = *(const bf16x8*)(pbase + roff + ((     16*g) ^ sw));
            const bf16x8 pa1 = *(const bf16x8*)(pbase + roff + ((64 + 16*g) ^ sw));
            float fr[4];
#pragma unroll
            for (int j = 0; j < 4; ++j) fr[j] = __shfl(fsc, 4*g + j, 64);
#pragma unroll
            for (int j = 0; j < 4; ++j) {
                oa0[j] *= fr[j]; oa1[j] *= fr[j]; oa2[j] *= fr[j]; oa3[j] *= fr[j];
            }

            // ---- 7. PV (compiler's counted V-wait) ----
            __builtin_amdgcn_s_setprio(1);
            oa0 = MFMA16(pa0, v00, oa0); oa1 = MFMA16(pa0, v01, oa1);
            oa2 = MFMA16(pa0, v02, oa2); oa3 = MFMA16(pa0, v03, oa3);
            oa0 = MFMA16(pa1, v10, oa0); oa1 = MFMA16(pa1, v11, oa1);
            oa2 = MFMA16(pa1, v12, oa2); oa3 = MFMA16(pa1, v13, oa3);
            __builtin_amdgcn_s_setprio(0);
            __builtin_amdgcn_sched_barrier(0);

            // ---- 8. V(next) ----
            LOADV(ktn);
            __builtin_amdgcn_sched_barrier(0);
            bcur = bnxt;
        }
    }
#undef LOADK
#undef LOADV

    // ---- epilogue: normalize + write (b, q, h*64+dv) fp32 ----
    const float inv = 1.0f / l_run;
    float ir[4];
#pragma unroll
    for (int j = 0; j < 4; ++j) ir[j] = __shfl(inv, 4*g + j, 64);
    const int bb = bh >> 3, h = bh & 7;
    const f32x4 oav[4] = {oa0, oa1, oa2, oa3};
#pragma unroll
    for (int nt = 0; nt < 4; ++nt)
#pragma unroll
        for (int j = 0; j < 4; ++j)
            O[((size_t)(bb*NQ_ + q0 + 4*g + j))*DM_ + h*64 + 16*nt + r] = oav[nt][j] * ir[j];
}

// ---------------------------------------------------------------------------
extern "C" void kernel_launch(void* const* d_in, const int* in_sizes, int n_in,
                              void* d_out, int out_size, void* d_ws, size_t ws_size,
                              hipStream_t stream) {
    (void)in_sizes; (void)n_in; (void)out_size; (void)ws_size;

    const float* q    = (const float*)d_in[0];
    const float* k    = (const float*)d_in[1];
    const float* v    = (const float*)d_in[2];
    const float* attw = (const float*)d_in[3];
    const unsigned char* mask = (const unsigned char*)d_in[4];
    const float* Wq = (const float*)d_in[5];
    const float* bq = (const float*)d_in[6];
    const float* Wk = (const float*)d_in[7];
    const float* bk = (const float*)d_in[8];
    const float* Wv = (const float*)d_in[9];
    const float* bv = (const float*)d_in[10];
    const float* Wo = (const float*)d_in[11];
    const float* bo = (const float*)d_in[12];
    float* out = (float*)d_out;

    // ws (shorts): q_bf[NE] k_bf[NE] vT[NE] wt[8*WL] | bits[2Mi u64] | o_ws fp32
    const long long NE = (long long)B_*H_*NQ_*DK_;        // 4Mi
    unsigned short* q_bf = (unsigned short*)d_ws;
    unsigned short* k_bf = q_bf + NE;
    unsigned short* vT   = q_bf + 2*NE;
    unsigned short* wt   = q_bf + 3*NE;
    unsigned long long* bits = (unsigned long long*)(wt + 8LL*WL_);
    const long long NB = (long long)B_*H_*NQ_*NK_/64;     // 2Mi
    float* o_ws = (float*)(bits + NB);

    // allow 130KB dynamic LDS for attn (idempotent, not a stream op)
    hipFuncSetAttribute(reinterpret_cast<const void*>(attn_mfma),
                        hipFuncAttributeMaxDynamicSharedMemorySize, 133120);

    const dim3 blk(256);
    wprep<<<dim3(8, 8, 4), blk, 0, stream>>>(Wq, Wk, Wv, Wo, wt);
    conv_mask<<<dim3(2048), blk, 0, stream>>>(mask, bits);

    const dim3 gg(128, 8);
    gemm_split<0><<<gg, blk, 0, stream>>>(q, wt + 0*WL_, wt + 1*WL_, bq, q_bf, 0.125f);
    gemm_split<0><<<gg, blk, 0, stream>>>(k, wt + 2*WL_, wt + 3*WL_, bk, k_bf, 1.0f);
    gemm_split<1><<<gg, blk, 0, stream>>>(v, wt + 4*WL_, wt + 5*WL_, bv, vT, 1.0f);

    attn_mfma<<<dim3(NQ_/64, B_*H_), blk, 133120, stream>>>(q_bf, k_bf, vT, attw, bits, o_ws);

    gemm_split<2><<<gg, blk, 0, stream>>>(o_ws, wt + 6*WL_, wt + 7*WL_, bo, out, 1.0f);
}

// Round 11
// 518.956 us; speedup vs baseline: 1.3457x; 1.0507x over previous
//
#include <hip/hip_runtime.h>
#include <hip/hip_bf16.h>
#include <math.h>

#define B_   4
#define H_   8
#define NQ_  2048
#define NK_  2048
#define DM_  512
#define DK_  64
#define WL_  262144   // 512*512

typedef short  bf16x8 __attribute__((ext_vector_type(8)));
typedef float  f32x4  __attribute__((ext_vector_type(4)));
typedef __attribute__((address_space(3))) float lds_f;

static __device__ __forceinline__ f32x4 MFMA16(bf16x8 a, bf16x8 b, f32x4 c) {
    return __builtin_amdgcn_mfma_f32_16x16x32_bf16(a, b, c, 0, 0, 0);
}
static __device__ __forceinline__ unsigned short f2bf(float f) {
    __hip_bfloat16 h = __float2bfloat16(f);
    unsigned short u; __builtin_memcpy(&u, &h, 2); return u;
}
static __device__ __forceinline__ float bf2f(unsigned short u) {
    unsigned int x = ((unsigned int)u) << 16;
    float f; __builtin_memcpy(&f, &x, 4); return f;
}
static __device__ __forceinline__ void glds16(const void* g, void* l) {
    __builtin_amdgcn_global_load_lds(
        (__attribute__((address_space(1))) const void*)g,
        (__attribute__((address_space(3))) void*)l, 16, 0, 0);
}

// ---------------------------------------------------------------------------
// mask -> bitmask, coalesced (lane-contiguous uint4 loads, grid-stride)
// ---------------------------------------------------------------------------
__global__ __launch_bounds__(256) void conv_mask(const unsigned char* __restrict__ Mk,
                                                 unsigned long long* __restrict__ bits)
{
    __shared__ int s_flag;
    const int tid = threadIdx.x;
    if (tid == 0) s_flag = 0;
    __syncthreads();
    {
        bool any = false;
#pragma unroll
        for (int i = 1; i < 16; i += 4)
            if (Mk[tid*16 + i]) any = true;
        if (any) s_flag = 1;
    }
    __syncthreads();

    const long long NELEM = (long long)B_*H_*NQ_*NK_;      // 128Mi
    const long long nth   = (long long)gridDim.x * 256;
    const long long T     = (long long)blockIdx.x * 256 + tid;
    unsigned short* b16   = (unsigned short*)bits;
    const uint4*    src   = (const uint4*)Mk;

    if (s_flag) {
        const long long n = NELEM / 16;
        for (long long t = T; t < n; t += nth) {
            const uint4 u = src[t];
            const unsigned int w[4] = {u.x, u.y, u.z, u.w};
            unsigned int m = 0;
#pragma unroll
            for (int j = 0; j < 4; ++j)
#pragma unroll
                for (int b2 = 0; b2 < 4; ++b2)
                    if ((w[j] >> (8*b2)) & 0xffu) m |= 1u << (4*j + b2);
            b16[t] = (unsigned short)m;
        }
    } else {
        const long long n = NELEM / 4;
        const int l3 = tid & 3;
        for (long long t = T; t < n; t += nth) {
            const uint4 u = src[t];
            const unsigned int nib = (u.x ? 1u : 0u) | (u.y ? 2u : 0u) |
                                     (u.z ? 4u : 0u) | (u.w ? 8u : 0u);
            unsigned int v = nib << (4*l3);
            v |= __shfl_xor(v, 1, 64);
            v |= __shfl_xor(v, 2, 64);
            if (l3 == 0) b16[t >> 2] = (unsigned short)v;
        }
    }
}

// ---------------------------------------------------------------------------
// W (512x512 fp32, [k][n]) -> WT_hi/WT_lo (bf16, [n][k]) for all 4 weights
// ---------------------------------------------------------------------------
__global__ __launch_bounds__(256) void wprep(const float* __restrict__ Wq,
                                             const float* __restrict__ Wk,
                                             const float* __restrict__ Wv,
                                             const float* __restrict__ Wo,
                                             unsigned short* __restrict__ out)
{
    __shared__ float tile[64][65];
    const int tid = threadIdx.x;
    const int k0 = blockIdx.x * 64, n0 = blockIdx.y * 64, w = blockIdx.z;
    const float* W = (w == 0) ? Wq : (w == 1) ? Wk : (w == 2) ? Wv : Wo;
    unsigned short* WTh = out + (size_t)w * 2 * WL_;
    unsigned short* WTl = WTh + WL_;

#pragma unroll
    for (int rd = 0; rd < 4; ++rd) {
        const int k = (tid >> 4) + 16*rd, c4 = (tid & 15) * 4;
        const float4 v4 = *(const float4*)(W + (size_t)(k0 + k)*DM_ + n0 + c4);
        tile[k][c4+0] = v4.x; tile[k][c4+1] = v4.y;
        tile[k][c4+2] = v4.z; tile[k][c4+3] = v4.w;
    }
    __syncthreads();
#pragma unroll
    for (int rd = 0; rd < 4; ++rd) {
        const int n = (tid >> 4) + 16*rd, kk = (tid & 15) * 4;
        unsigned short hh[4], ll[4];
#pragma unroll
        for (int j = 0; j < 4; ++j) {
            const float f = tile[kk + j][n];
            hh[j] = f2bf(f);
            ll[j] = f2bf(f - bf2f(hh[j]));
        }
        *(ushort4*)(WTh + (size_t)(n0 + n)*DM_ + k0 + kk) = make_ushort4(hh[0],hh[1],hh[2],hh[3]);
        *(ushort4*)(WTl + (size_t)(n0 + n)*DM_ + k0 + kk) = make_ushort4(ll[0],ll[1],ll[2],ll[3]);
    }
}

// ---------------------------------------------------------------------------
// Split-bf16 MFMA GEMM: C = A(fp32) @ W + bias (x oscale).
// MODE 0/1: 2-term (Ah*Wh + Ah*Wl) -> bf16 out.  MODE 2: 3-term -> fp32 out.
// ---------------------------------------------------------------------------
template<int MODE>
__global__ __launch_bounds__(256) void gemm_split(
    const float* __restrict__ A,
    const unsigned short* __restrict__ WTh,
    const unsigned short* __restrict__ WTl,
    const float* __restrict__ bias,
    void* __restrict__ outv, const float oscale)
{
    __shared__ unsigned short Ah[64][64], Al[64][64], Bh[64][64], Bl[64][64];

    const int tid = threadIdx.x;
    const int w = tid >> 6, lane = tid & 63, g = lane >> 4, r = lane & 15;
    const int m0 = blockIdx.x * 64, n0 = blockIdx.y * 64;

    char* pAh = (char*)&Ah[0][0];
    char* pAl = (char*)&Al[0][0];
    char* pBh = (char*)&Bh[0][0];
    char* pBl = (char*)&Bl[0][0];

    const f32x4 z4 = {0.f, 0.f, 0.f, 0.f};
    f32x4 acc[4] = {z4, z4, z4, z4};

    for (int kt = 0; kt < DM_; kt += 64) {
#pragma unroll
        for (int rd = 0; rd < 4; ++rd) {
            const int row = (tid >> 4) + 16*rd;
            const int c4  = (tid & 15) * 4;
            const float4 a4 = *(const float4*)(A + (size_t)(m0 + row)*DM_ + kt + c4);
            const float av[4] = {a4.x, a4.y, a4.z, a4.w};
            unsigned short hh[4];
#pragma unroll
            for (int j = 0; j < 4; ++j) hh[j] = f2bf(av[j]);
            const int bo = (c4 * 2) ^ ((row & 7) << 4);
            *(ushort4*)(pAh + row*128 + bo) = make_ushort4(hh[0],hh[1],hh[2],hh[3]);
            if (MODE == 2) {
                unsigned short ll[4];
#pragma unroll
                for (int j = 0; j < 4; ++j) ll[j] = f2bf(av[j] - bf2f(hh[j]));
                *(ushort4*)(pAl + row*128 + bo) = make_ushort4(ll[0],ll[1],ll[2],ll[3]);
            }
        }
#pragma unroll
        for (int rd = 0; rd < 2; ++rd) {
            const int idx = tid + 256*rd;
            const int row = idx >> 3;
            const int cb  = (idx & 7) * 16;
            const int bo  = cb ^ ((row & 7) << 4);
            const size_t goff = (size_t)(n0 + row)*DM_ + kt + (cb >> 1);
            *(bf16x8*)(pBh + row*128 + bo) = *(const bf16x8*)(WTh + goff);
            *(bf16x8*)(pBl + row*128 + bo) = *(const bf16x8*)(WTl + goff);
        }
        __syncthreads();

        const int swr = (r & 7) << 4;
#pragma unroll
        for (int ks = 0; ks < 2; ++ks) {
            const int xo = (64*ks + 16*g) ^ swr;
            const bf16x8 xh = *(const bf16x8*)(pAh + (16*w + r)*128 + xo);
#pragma unroll
            for (int nt = 0; nt < 4; ++nt) {
                const bf16x8 bh = *(const bf16x8*)(pBh + (16*nt + r)*128 + xo);
                const bf16x8 bl = *(const bf16x8*)(pBl + (16*nt + r)*128 + xo);
                if (MODE == 1) {
                    acc[nt] = MFMA16(xh, bh, acc[nt]);
                    acc[nt] = MFMA16(xh, bl, acc[nt]);
                } else if (MODE == 0) {
                    acc[nt] = MFMA16(bh, xh, acc[nt]);
                    acc[nt] = MFMA16(bl, xh, acc[nt]);
                } else {
                    const bf16x8 xl = *(const bf16x8*)(pAl + (16*w + r)*128 + xo);
                    acc[nt] = MFMA16(bh, xh, acc[nt]);
                    acc[nt] = MFMA16(bh, xl, acc[nt]);
                    acc[nt] = MFMA16(bl, xh, acc[nt]);
                }
            }
        }
        __syncthreads();
    }

    if (MODE == 0) {
        const int m = m0 + 16*w + r;
        const int b = m >> 11, q = m & 2047, h = blockIdx.y;
        unsigned short* dst = (unsigned short*)outv + (((size_t)(b*H_ + h))*NQ_ + q)*DK_;
#pragma unroll
        for (int nt = 0; nt < 4; ++nt) {
            unsigned short u[4];
#pragma unroll
            for (int j = 0; j < 4; ++j)
                u[j] = f2bf((acc[nt][j] + bias[n0 + 16*nt + 4*g + j]) * oscale);
            *(ushort4*)(dst + 16*nt + 4*g) = make_ushort4(u[0],u[1],u[2],u[3]);
        }
    } else if (MODE == 1) {
        const int b = m0 >> 11, h = blockIdx.y;
        const int key = (m0 & 2047) + 16*w + 4*g;
#pragma unroll
        for (int nt = 0; nt < 4; ++nt) {
            const int dv = 16*nt + r;
            const float bv = bias[n0 + dv];
            unsigned short u[4];
#pragma unroll
            for (int j = 0; j < 4; ++j) u[j] = f2bf(acc[nt][j] + bv);
            *(ushort4*)((unsigned short*)outv +
                        (((size_t)(b*H_ + h))*DK_ + dv)*NK_ + key) = make_ushort4(u[0],u[1],u[2],u[3]);
        }
    } else {
        const int m = m0 + 16*w + r;
        float* dst = (float*)outv + (size_t)m*DM_ + n0;
#pragma unroll
        for (int nt = 0; nt < 4; ++nt) {
            float4 o4;
            o4.x = acc[nt][0] + bias[n0 + 16*nt + 4*g + 0];
            o4.y = acc[nt][1] + bias[n0 + 16*nt + 4*g + 1];
            o4.z = acc[nt][2] + bias[n0 + 16*nt + 4*g + 2];
            o4.w = acc[nt][3] + bias[n0 + 16*nt + 4*g + 3];
            *(float4*)(dst + 16*nt + 4*g) = o4;
        }
    }
}

// ---------------------------------------------------------------------------
// MFMA flash attention. 4 waves = 4 q-subblocks of 16 rows; K-step 64.
// THIS ROUND: LDS cut 133KB -> 41KB (64-key W tiles, double-buffered) so
// 3 blocks/CU = 12 waves/CU (was 1 block = 4 waves). W staged per iter:
// 4 glds/wave (4-row x 256B chunks), source-granule XOR swizzle, quad-packed
// LDS (4 rows x 264 floats incl pad). Counted vmcnt(30); asm ds_read.
// ---------------------------------------------------------------------------
__global__ __launch_bounds__(256) void attn_mfma(
    const unsigned short* __restrict__ Qb,
    const unsigned short* __restrict__ Kb,
    const unsigned short* __restrict__ Vt,
    const float* __restrict__ Wt,
    const unsigned long long* __restrict__ Mb,
    float* __restrict__ O)
{
    __shared__ float Wlds[2][4][1056];   // [buf][wave][4 quads x (4x64 + 8 pad)]
    __shared__ short Pl[4][1024];        // P bounce, 2KB/wave

    const int tid  = threadIdx.x;
    const int wv   = tid >> 6, lane = tid & 63;
    const int g    = lane >> 4, r = lane & 15;
    const int q0   = blockIdx.x * 64 + wv * 16;
    const int bh   = blockIdx.y;

    const size_t kvBase = (size_t)bh * NK_ * DK_;
    const unsigned short* qp = Qb + kvBase + (size_t)(q0 + r)*DK_ + 8*g;
    const bf16x8 qf0 = *(const bf16x8*)qp;
    const bf16x8 qf1 = *(const bf16x8*)(qp + 32);
    __builtin_amdgcn_sched_barrier(0);

    const float* wbase_g = Wt + ((size_t)bh*NQ_ + q0)*NK_;   // wave's 16 rows
    const unsigned long long* brow = Mb + ((size_t)bh*NQ_ + q0 + r)*(NK_/64);
    const unsigned short* kbase = Kb + kvBase + (size_t)r*DK_ + 8*g;
    const unsigned short* vbase = Vt + kvBase + (size_t)r*NK_ + 8*g;

    const f32x4 zero4 = {0.f, 0.f, 0.f, 0.f};
    f32x4 oa0 = zero4, oa1 = zero4, oa2 = zero4, oa3 = zero4;
    float m_run = -1e30f, l_run = 0.f;

    char* pbase = (char*)&Pl[wv][0];
    const int roff = r * 128;
    const int sw   = (r & 7) << 4;

    // stage 64-key tile at kt into buffer pbuf: 4 glds, each covering 4 rows
    // x 256B. LDS slot gg of row j holds global granule gg^(4j) (bank spread).
    const int sj  = lane >> 4;                    // row within quad
    const int sgg = (lane & 15) ^ (4*(lane >> 4));// source granule (swizzled)
    auto stage = [&](int pbuf, int kt) {
        float* dstb = &Wlds[pbuf][wv][0];
        const float* srcb = wbase_g + kt + 4*sgg;
#pragma unroll
        for (int qd = 0; qd < 4; ++qd)
            glds16(srcb + (size_t)(qd*4 + sj)*NK_, dstb + qd*264);
    };

    bf16x8 k00,k01,k10,k11,k20,k21,k30,k31;
    bf16x8 v00,v01,v02,v03, v10,v11,v12,v13;

#define LOADK(ktv) do { \
    const unsigned short* kp_ = kbase + (size_t)(ktv)*DK_;      \
    k00 = *(const bf16x8*)kp_;         k01 = *(const bf16x8*)(kp_ + 32);          \
    k10 = *(const bf16x8*)(kp_+1024);  k11 = *(const bf16x8*)(kp_ + 1024 + 32);   \
    k20 = *(const bf16x8*)(kp_+2048);  k21 = *(const bf16x8*)(kp_ + 2048 + 32);   \
    k30 = *(const bf16x8*)(kp_+3072);  k31 = *(const bf16x8*)(kp_ + 3072 + 32);   \
} while (0)

#define LOADV(ktv) do { \
    const unsigned short* vp_ = vbase + (ktv);                  \
    v00 = *(const bf16x8*)(vp_);             v01 = *(const bf16x8*)(vp_ + 16*NK_);      \
    v02 = *(const bf16x8*)(vp_ + 32*NK_);    v03 = *(const bf16x8*)(vp_ + 48*NK_);      \
    v10 = *(const bf16x8*)(vp_ + 32);        v11 = *(const bf16x8*)(vp_ + 16*NK_ + 32); \
    v12 = *(const bf16x8*)(vp_ + 32*NK_+32); v13 = *(const bf16x8*)(vp_ + 48*NK_ + 32); \
} while (0)

    // ---- prologue: stage(0), bits, K(0), V(0) ----
    stage(0, 0);
    __builtin_amdgcn_sched_barrier(0);
    unsigned long long bcur = brow[0];
    LOADK(0);
    LOADV(0);
    __builtin_amdgcn_sched_barrier(0);

#pragma unroll 1
    for (int i = 0; i < 32; ++i) {
        const int p   = i & 1;
        const int in_ = (i + 1 < 32) ? i + 1 : i;
        const int ktn = in_ * 64;

        // ---- 1. QK MFMA (counted K-wait also FIFO-drains stage(i)) ----
        f32x4 sa0 = zero4, sa1 = zero4, sa2 = zero4, sa3 = zero4;
        __builtin_amdgcn_s_setprio(1);
        sa0 = MFMA16(k00, qf0, sa0); sa0 = MFMA16(k01, qf1, sa0);
        sa1 = MFMA16(k10, qf0, sa1); sa1 = MFMA16(k11, qf1, sa1);
        sa2 = MFMA16(k20, qf0, sa2); sa2 = MFMA16(k21, qf1, sa2);
        sa3 = MFMA16(k30, qf0, sa3); sa3 = MFMA16(k31, qf1, sa3);
        __builtin_amdgcn_s_setprio(0);
        __builtin_amdgcn_sched_barrier(0);

        // ---- 2. issue next-iter prefetches: stage, bits, K ----
        stage(p ^ 1, ktn);
        const unsigned long long bnxt = brow[in_];
        LOADK(ktn);
        __builtin_amdgcn_sched_barrier(0);

        // ---- 3. counted drain (stage(i) older than last 30 ops) ----
        asm volatile("s_waitcnt vmcnt(30)" ::: "memory");
        __builtin_amdgcn_sched_barrier(0);

        // ---- 4. W fragments: row r -> quad r>>2, sub-row r&3 ----
        f32x4 wf[4];
        {
            lds_f* wrp = (lds_f*)(&Wlds[p][wv][0]) + (r >> 2)*264 + (r & 3)*64;
            const int jx = 4*(r & 3);
#pragma unroll
            for (int t = 0; t < 4; ++t) {
                lds_f* a = wrp + 4*((4*t + g) ^ jx);
                asm volatile("ds_read_b128 %0, %1" : "=v"(wf[t]) : "v"(a));
            }
        }
        asm volatile("s_waitcnt lgkmcnt(0)" ::: "memory");
        __builtin_amdgcn_sched_barrier(0);

        // ---- 5. logits + online softmax ----
        float lg[16];
        const f32x4 sav[4] = {sa0, sa1, sa2, sa3};
#pragma unroll
        for (int t = 0; t < 4; ++t) {
            const unsigned int half = (t & 2) ? (unsigned int)(bcur >> 32)
                                              : (unsigned int)bcur;
#pragma unroll
            for (int j = 0; j < 4; ++j) {
                const unsigned int bit = (half >> (16*(t & 1) + 4*g + j)) & 1u;
                lg[4*t+j] = bit ? -1e30f : sav[t][j] * wf[t][j];
            }
        }
        float mx = lg[0];
#pragma unroll
        for (int i2 = 1; i2 < 16; ++i2) mx = fmaxf(mx, lg[i2]);
        mx = fmaxf(mx, __shfl_xor(mx, 16, 64));
        mx = fmaxf(mx, __shfl_xor(mx, 32, 64));
        const float mnew = fmaxf(m_run, mx);
        const float fsc  = __expf(m_run - mnew);
        m_run = mnew;
        float p16[16], rs = 0.f;
#pragma unroll
        for (int i2 = 0; i2 < 16; ++i2) { p16[i2] = __expf(lg[i2] - mnew); rs += p16[i2]; }
        rs += __shfl_xor(rs, 16, 64);
        rs += __shfl_xor(rs, 32, 64);
        l_run = l_run * fsc + rs;
        __builtin_amdgcn_sched_barrier(0);

        // ---- 6. P pack + O rescale ----
#pragma unroll
        for (int t = 0; t < 4; ++t) {
            const unsigned int w0 = (unsigned int)f2bf(p16[4*t+0]) |
                                    ((unsigned int)f2bf(p16[4*t+1]) << 16);
            const unsigned int w1 = (unsigned int)f2bf(p16[4*t+2]) |
                                    ((unsigned int)f2bf(p16[4*t+3]) << 16);
            *(int2*)(pbase + roff + ((32*t + 8*g) ^ sw)) = make_int2((int)w0, (int)w1);
        }
        asm volatile("s_waitcnt lgkmcnt(0)" ::: "memory");
        __builtin_amdgcn_sched_barrier(0);
        const bf16x8 pa0 = *(const bf16x8*)(pbase + roff + ((     16*g) ^ sw));
        const bf16x8 pa1 = *(const bf16x8*)(pbase + roff + ((64 + 16*g) ^ sw));
        float fr[4];
#pragma unroll
        for (int j = 0; j < 4; ++j) fr[j] = __shfl(fsc, 4*g + j, 64);
#pragma unroll
        for (int j = 0; j < 4; ++j) {
            oa0[j] *= fr[j]; oa1[j] *= fr[j]; oa2[j] *= fr[j]; oa3[j] *= fr[j];
        }

        // ---- 7. PV (compiler's counted V-wait) ----
        __builtin_amdgcn_s_setprio(1);
        oa0 = MFMA16(pa0, v00, oa0); oa1 = MFMA16(pa0, v01, oa1);
        oa2 = MFMA16(pa0, v02, oa2); oa3 = MFMA16(pa0, v03, oa3);
        oa0 = MFMA16(pa1, v10, oa0); oa1 = MFMA16(pa1, v11, oa1);
        oa2 = MFMA16(pa1, v12, oa2); oa3 = MFMA16(pa1, v13, oa3);
        __builtin_amdgcn_s_setprio(0);
        __builtin_amdgcn_sched_barrier(0);

        // ---- 8. V(next) ----
        LOADV(ktn);
        __builtin_amdgcn_sched_barrier(0);
        bcur = bnxt;
    }
#undef LOADK
#undef LOADV

    // ---- epilogue: normalize + write (b, q, h*64+dv) fp32 ----
    const float inv = 1.0f / l_run;
    float ir[4];
#pragma unroll
    for (int j = 0; j < 4; ++j) ir[j] = __shfl(inv, 4*g + j, 64);
    const int bb = bh >> 3, h = bh & 7;
    const f32x4 oav[4] = {oa0, oa1, oa2, oa3};
#pragma unroll
    for (int nt = 0; nt < 4; ++nt)
#pragma unroll
        for (int j = 0; j < 4; ++j)
            O[((size_t)(bb*NQ_ + q0 + 4*g + j))*DM_ + h*64 + 16*nt + r] = oav[nt][j] * ir[j];
}

// ---------------------------------------------------------------------------
extern "C" void kernel_launch(void* const* d_in, const int* in_sizes, int n_in,
                              void* d_out, int out_size, void* d_ws, size_t ws_size,
                              hipStream_t stream) {
    (void)in_sizes; (void)n_in; (void)out_size; (void)ws_size;

    const float* q    = (const float*)d_in[0];
    const float* k    = (const float*)d_in[1];
    const float* v    = (const float*)d_in[2];
    const float* attw = (const float*)d_in[3];
    const unsigned char* mask = (const unsigned char*)d_in[4];
    const float* Wq = (const float*)d_in[5];
    const float* bq = (const float*)d_in[6];
    const float* Wk = (const float*)d_in[7];
    const float* bk = (const float*)d_in[8];
    const float* Wv = (const float*)d_in[9];
    const float* bv = (const float*)d_in[10];
    const float* Wo = (const float*)d_in[11];
    const float* bo = (const float*)d_in[12];
    float* out = (float*)d_out;

    // ws (shorts): q_bf[NE] k_bf[NE] vT[NE] wt[8*WL] | bits[2Mi u64] | o_ws fp32
    const long long NE = (long long)B_*H_*NQ_*DK_;        // 4Mi
    unsigned short* q_bf = (unsigned short*)d_ws;
    unsigned short* k_bf = q_bf + NE;
    unsigned short* vT   = q_bf + 2*NE;
    unsigned short* wt   = q_bf + 3*NE;
    unsigned long long* bits = (unsigned long long*)(wt + 8LL*WL_);
    const long long NB = (long long)B_*H_*NQ_*NK_/64;     // 2Mi
    float* o_ws = (float*)(bits + NB);

    const dim3 blk(256);
    wprep<<<dim3(8, 8, 4), blk, 0, stream>>>(Wq, Wk, Wv, Wo, wt);
    conv_mask<<<dim3(2048), blk, 0, stream>>>(mask, bits);

    const dim3 gg(128, 8);
    gemm_split<0><<<gg, blk, 0, stream>>>(q, wt + 0*WL_, wt + 1*WL_, bq, q_bf, 0.125f);
    gemm_split<0><<<gg, blk, 0, stream>>>(k, wt + 2*WL_, wt + 3*WL_, bk, k_bf, 1.0f);
    gemm_split<1><<<gg, blk, 0, stream>>>(v, wt + 4*WL_, wt + 5*WL_, bv, vT, 1.0f);

    attn_mfma<<<dim3(NQ_/64, B_*H_), blk, 0, stream>>>(q_bf, k_bf, vT, attw, bits, o_ws);

    gemm_split<2><<<gg, blk, 0, stream>>>(o_ws, wt + 6*WL_, wt + 7*WL_, bo, out, 1.0f);
}

// Round 12
// 518.644 us; speedup vs baseline: 1.3466x; 1.0006x over previous
//
#include <hip/hip_runtime.h>
#include <hip/hip_bf16.h>
#include <math.h>

#define B_   4
#define H_   8
#define NQ_  2048
#define NK_  2048
#define DM_  512
#define DK_  64
#define WL_  262144   // 512*512

typedef short  bf16x8 __attribute__((ext_vector_type(8)));
typedef float  f32x4  __attribute__((ext_vector_type(4)));
typedef __attribute__((address_space(3))) float lds_f;

static __device__ __forceinline__ f32x4 MFMA16(bf16x8 a, bf16x8 b, f32x4 c) {
    return __builtin_amdgcn_mfma_f32_16x16x32_bf16(a, b, c, 0, 0, 0);
}
static __device__ __forceinline__ unsigned short f2bf(float f) {
    __hip_bfloat16 h = __float2bfloat16(f);
    unsigned short u; __builtin_memcpy(&u, &h, 2); return u;
}
static __device__ __forceinline__ float bf2f(unsigned short u) {
    unsigned int x = ((unsigned int)u) << 16;
    float f; __builtin_memcpy(&f, &x, 4); return f;
}
static __device__ __forceinline__ void glds16(const void* g, void* l) {
    __builtin_amdgcn_global_load_lds(
        (__attribute__((address_space(1))) const void*)g,
        (__attribute__((address_space(3))) void*)l, 16, 0, 0);
}

// ---------------------------------------------------------------------------
// mask -> bitmask, coalesced (lane-contiguous uint4 loads, grid-stride)
// ---------------------------------------------------------------------------
__global__ __launch_bounds__(256) void conv_mask(const unsigned char* __restrict__ Mk,
                                                 unsigned long long* __restrict__ bits)
{
    __shared__ int s_flag;
    const int tid = threadIdx.x;
    if (tid == 0) s_flag = 0;
    __syncthreads();
    {
        bool any = false;
#pragma unroll
        for (int i = 1; i < 16; i += 4)
            if (Mk[tid*16 + i]) any = true;
        if (any) s_flag = 1;
    }
    __syncthreads();

    const long long NELEM = (long long)B_*H_*NQ_*NK_;      // 128Mi
    const long long nth   = (long long)gridDim.x * 256;
    const long long T     = (long long)blockIdx.x * 256 + tid;
    unsigned short* b16   = (unsigned short*)bits;
    const uint4*    src   = (const uint4*)Mk;

    if (s_flag) {
        const long long n = NELEM / 16;
        for (long long t = T; t < n; t += nth) {
            const uint4 u = src[t];
            const unsigned int w[4] = {u.x, u.y, u.z, u.w};
            unsigned int m = 0;
#pragma unroll
            for (int j = 0; j < 4; ++j)
#pragma unroll
                for (int b2 = 0; b2 < 4; ++b2)
                    if ((w[j] >> (8*b2)) & 0xffu) m |= 1u << (4*j + b2);
            b16[t] = (unsigned short)m;
        }
    } else {
        const long long n = NELEM / 4;
        const int l3 = tid & 3;
        for (long long t = T; t < n; t += nth) {
            const uint4 u = src[t];
            const unsigned int nib = (u.x ? 1u : 0u) | (u.y ? 2u : 0u) |
                                     (u.z ? 4u : 0u) | (u.w ? 8u : 0u);
            unsigned int v = nib << (4*l3);
            v |= __shfl_xor(v, 1, 64);
            v |= __shfl_xor(v, 2, 64);
            if (l3 == 0) b16[t >> 2] = (unsigned short)v;
        }
    }
}

// ---------------------------------------------------------------------------
// W (512x512 fp32, [k][n]) -> WT_hi/WT_lo (bf16, [n][k]) for all 4 weights
// ---------------------------------------------------------------------------
__global__ __launch_bounds__(256) void wprep(const float* __restrict__ Wq,
                                             const float* __restrict__ Wk,
                                             const float* __restrict__ Wv,
                                             const float* __restrict__ Wo,
                                             unsigned short* __restrict__ out)
{
    __shared__ float tile[64][65];
    const int tid = threadIdx.x;
    const int k0 = blockIdx.x * 64, n0 = blockIdx.y * 64, w = blockIdx.z;
    const float* W = (w == 0) ? Wq : (w == 1) ? Wk : (w == 2) ? Wv : Wo;
    unsigned short* WTh = out + (size_t)w * 2 * WL_;
    unsigned short* WTl = WTh + WL_;

#pragma unroll
    for (int rd = 0; rd < 4; ++rd) {
        const int k = (tid >> 4) + 16*rd, c4 = (tid & 15) * 4;
        const float4 v4 = *(const float4*)(W + (size_t)(k0 + k)*DM_ + n0 + c4);
        tile[k][c4+0] = v4.x; tile[k][c4+1] = v4.y;
        tile[k][c4+2] = v4.z; tile[k][c4+3] = v4.w;
    }
    __syncthreads();
#pragma unroll
    for (int rd = 0; rd < 4; ++rd) {
        const int n = (tid >> 4) + 16*rd, kk = (tid & 15) * 4;
        unsigned short hh[4], ll[4];
#pragma unroll
        for (int j = 0; j < 4; ++j) {
            const float f = tile[kk + j][n];
            hh[j] = f2bf(f);
            ll[j] = f2bf(f - bf2f(hh[j]));
        }
        *(ushort4*)(WTh + (size_t)(n0 + n)*DM_ + k0 + kk) = make_ushort4(hh[0],hh[1],hh[2],hh[3]);
        *(ushort4*)(WTl + (size_t)(n0 + n)*DM_ + k0 + kk) = make_ushort4(ll[0],ll[1],ll[2],ll[3]);
    }
}

// ---------------------------------------------------------------------------
// Split-bf16 MFMA GEMM: C = A(fp32) @ W + bias (x oscale).
// MODE 0/1: 2-term (Ah*Wh + Ah*Wl) -> bf16 out.  MODE 2: 3-term -> fp32 out.
// ---------------------------------------------------------------------------
template<int MODE>
__global__ __launch_bounds__(256) void gemm_split(
    const float* __restrict__ A,
    const unsigned short* __restrict__ WTh,
    const unsigned short* __restrict__ WTl,
    const float* __restrict__ bias,
    void* __restrict__ outv, const float oscale)
{
    __shared__ unsigned short Ah[64][64], Al[64][64], Bh[64][64], Bl[64][64];

    const int tid = threadIdx.x;
    const int w = tid >> 6, lane = tid & 63, g = lane >> 4, r = lane & 15;
    const int m0 = blockIdx.x * 64, n0 = blockIdx.y * 64;

    char* pAh = (char*)&Ah[0][0];
    char* pAl = (char*)&Al[0][0];
    char* pBh = (char*)&Bh[0][0];
    char* pBl = (char*)&Bl[0][0];

    const f32x4 z4 = {0.f, 0.f, 0.f, 0.f};
    f32x4 acc[4] = {z4, z4, z4, z4};

    for (int kt = 0; kt < DM_; kt += 64) {
#pragma unroll
        for (int rd = 0; rd < 4; ++rd) {
            const int row = (tid >> 4) + 16*rd;
            const int c4  = (tid & 15) * 4;
            const float4 a4 = *(const float4*)(A + (size_t)(m0 + row)*DM_ + kt + c4);
            const float av[4] = {a4.x, a4.y, a4.z, a4.w};
            unsigned short hh[4];
#pragma unroll
            for (int j = 0; j < 4; ++j) hh[j] = f2bf(av[j]);
            const int bo = (c4 * 2) ^ ((row & 7) << 4);
            *(ushort4*)(pAh + row*128 + bo) = make_ushort4(hh[0],hh[1],hh[2],hh[3]);
            if (MODE == 2) {
                unsigned short ll[4];
#pragma unroll
                for (int j = 0; j < 4; ++j) ll[j] = f2bf(av[j] - bf2f(hh[j]));
                *(ushort4*)(pAl + row*128 + bo) = make_ushort4(ll[0],ll[1],ll[2],ll[3]);
            }
        }
#pragma unroll
        for (int rd = 0; rd < 2; ++rd) {
            const int idx = tid + 256*rd;
            const int row = idx >> 3;
            const int cb  = (idx & 7) * 16;
            const int bo  = cb ^ ((row & 7) << 4);
            const size_t goff = (size_t)(n0 + row)*DM_ + kt + (cb >> 1);
            *(bf16x8*)(pBh + row*128 + bo) = *(const bf16x8*)(WTh + goff);
            *(bf16x8*)(pBl + row*128 + bo) = *(const bf16x8*)(WTl + goff);
        }
        __syncthreads();

        const int swr = (r & 7) << 4;
#pragma unroll
        for (int ks = 0; ks < 2; ++ks) {
            const int xo = (64*ks + 16*g) ^ swr;
            const bf16x8 xh = *(const bf16x8*)(pAh + (16*w + r)*128 + xo);
#pragma unroll
            for (int nt = 0; nt < 4; ++nt) {
                const bf16x8 bh = *(const bf16x8*)(pBh + (16*nt + r)*128 + xo);
                const bf16x8 bl = *(const bf16x8*)(pBl + (16*nt + r)*128 + xo);
                if (MODE == 1) {
                    acc[nt] = MFMA16(xh, bh, acc[nt]);
                    acc[nt] = MFMA16(xh, bl, acc[nt]);
                } else if (MODE == 0) {
                    acc[nt] = MFMA16(bh, xh, acc[nt]);
                    acc[nt] = MFMA16(bl, xh, acc[nt]);
                } else {
                    const bf16x8 xl = *(const bf16x8*)(pAl + (16*w + r)*128 + xo);
                    acc[nt] = MFMA16(bh, xh, acc[nt]);
                    acc[nt] = MFMA16(bh, xl, acc[nt]);
                    acc[nt] = MFMA16(bl, xh, acc[nt]);
                }
            }
        }
        __syncthreads();
    }

    if (MODE == 0) {
        const int m = m0 + 16*w + r;
        const int b = m >> 11, q = m & 2047, h = blockIdx.y;
        unsigned short* dst = (unsigned short*)outv + (((size_t)(b*H_ + h))*NQ_ + q)*DK_;
#pragma unroll
        for (int nt = 0; nt < 4; ++nt) {
            unsigned short u[4];
#pragma unroll
            for (int j = 0; j < 4; ++j)
                u[j] = f2bf((acc[nt][j] + bias[n0 + 16*nt + 4*g + j]) * oscale);
            *(ushort4*)(dst + 16*nt + 4*g) = make_ushort4(u[0],u[1],u[2],u[3]);
        }
    } else if (MODE == 1) {
        const int b = m0 >> 11, h = blockIdx.y;
        const int key = (m0 & 2047) + 16*w + 4*g;
#pragma unroll
        for (int nt = 0; nt < 4; ++nt) {
            const int dv = 16*nt + r;
            const float bv = bias[n0 + dv];
            unsigned short u[4];
#pragma unroll
            for (int j = 0; j < 4; ++j) u[j] = f2bf(acc[nt][j] + bv);
            *(ushort4*)((unsigned short*)outv +
                        (((size_t)(b*H_ + h))*DK_ + dv)*NK_ + key) = make_ushort4(u[0],u[1],u[2],u[3]);
        }
    } else {
        const int m = m0 + 16*w + r;
        float* dst = (float*)outv + (size_t)m*DM_ + n0;
#pragma unroll
        for (int nt = 0; nt < 4; ++nt) {
            float4 o4;
            o4.x = acc[nt][0] + bias[n0 + 16*nt + 4*g + 0];
            o4.y = acc[nt][1] + bias[n0 + 16*nt + 4*g + 1];
            o4.z = acc[nt][2] + bias[n0 + 16*nt + 4*g + 2];
            o4.w = acc[nt][3] + bias[n0 + 16*nt + 4*g + 3];
            *(float4*)(dst + 16*nt + 4*g) = o4;
        }
    }
}

// ---------------------------------------------------------------------------
// MFMA flash attention. 4 waves = 4 q-subblocks of 16 rows; K-step 64.
// THIS ROUND: per-block PHASE STAGGER of the K-tile loop (i0 = (bx+7*bh)&31,
// online softmax is tile-order invariant). Breaks the GPU-wide lockstep
// column-march over W (all blocks reading the same 256B column stripe of an
// 8KB-strided row space at once -> HBM channel camping, ~1.8 TB/s delivered).
// Otherwise byte-identical to r11 (41KB LDS, 3 blocks/CU, counted vmcnt).
// ---------------------------------------------------------------------------
__global__ __launch_bounds__(256) void attn_mfma(
    const unsigned short* __restrict__ Qb,
    const unsigned short* __restrict__ Kb,
    const unsigned short* __restrict__ Vt,
    const float* __restrict__ Wt,
    const unsigned long long* __restrict__ Mb,
    float* __restrict__ O)
{
    __shared__ float Wlds[2][4][1056];   // [buf][wave][4 quads x (4x64 + 8 pad)]
    __shared__ short Pl[4][1024];        // P bounce, 2KB/wave

    const int tid  = threadIdx.x;
    const int wv   = tid >> 6, lane = tid & 63;
    const int g    = lane >> 4, r = lane & 15;
    const int q0   = blockIdx.x * 64 + wv * 16;
    const int bh   = blockIdx.y;

    const size_t kvBase = (size_t)bh * NK_ * DK_;
    const unsigned short* qp = Qb + kvBase + (size_t)(q0 + r)*DK_ + 8*g;
    const bf16x8 qf0 = *(const bf16x8*)qp;
    const bf16x8 qf1 = *(const bf16x8*)(qp + 32);
    __builtin_amdgcn_sched_barrier(0);

    const float* wbase_g = Wt + ((size_t)bh*NQ_ + q0)*NK_;   // wave's 16 rows
    const unsigned long long* brow = Mb + ((size_t)bh*NQ_ + q0 + r)*(NK_/64);
    const unsigned short* kbase = Kb + kvBase + (size_t)r*DK_ + 8*g;
    const unsigned short* vbase = Vt + kvBase + (size_t)r*NK_ + 8*g;

    const f32x4 zero4 = {0.f, 0.f, 0.f, 0.f};
    f32x4 oa0 = zero4, oa1 = zero4, oa2 = zero4, oa3 = zero4;
    float m_run = -1e30f, l_run = 0.f;

    char* pbase = (char*)&Pl[wv][0];
    const int roff = r * 128;
    const int sw   = (r & 7) << 4;

    // stage 64-key tile at kt into buffer pbuf: 4 glds, each covering 4 rows
    // x 256B. LDS slot gg of row j holds global granule gg^(4j) (bank spread).
    const int sj  = lane >> 4;                    // row within quad
    const int sgg = (lane & 15) ^ (4*(lane >> 4));// source granule (swizzled)
    auto stage = [&](int pbuf, int kt) {
        float* dstb = &Wlds[pbuf][wv][0];
        const float* srcb = wbase_g + kt + 4*sgg;
#pragma unroll
        for (int qd = 0; qd < 4; ++qd)
            glds16(srcb + (size_t)(qd*4 + sj)*NK_, dstb + qd*264);
    };

    bf16x8 k00,k01,k10,k11,k20,k21,k30,k31;
    bf16x8 v00,v01,v02,v03, v10,v11,v12,v13;

#define LOADK(ktv) do { \
    const unsigned short* kp_ = kbase + (size_t)(ktv)*DK_;      \
    k00 = *(const bf16x8*)kp_;         k01 = *(const bf16x8*)(kp_ + 32);          \
    k10 = *(const bf16x8*)(kp_+1024);  k11 = *(const bf16x8*)(kp_ + 1024 + 32);   \
    k20 = *(const bf16x8*)(kp_+2048);  k21 = *(const bf16x8*)(kp_ + 2048 + 32);   \
    k30 = *(const bf16x8*)(kp_+3072);  k31 = *(const bf16x8*)(kp_ + 3072 + 32);   \
} while (0)

#define LOADV(ktv) do { \
    const unsigned short* vp_ = vbase + (ktv);                  \
    v00 = *(const bf16x8*)(vp_);             v01 = *(const bf16x8*)(vp_ + 16*NK_);      \
    v02 = *(const bf16x8*)(vp_ + 32*NK_);    v03 = *(const bf16x8*)(vp_ + 48*NK_);      \
    v10 = *(const bf16x8*)(vp_ + 32);        v11 = *(const bf16x8*)(vp_ + 16*NK_ + 32); \
    v12 = *(const bf16x8*)(vp_ + 32*NK_+32); v13 = *(const bf16x8*)(vp_ + 48*NK_ + 32); \
} while (0)

    // ---- phase stagger: this block starts at tile i0, wraps mod 32 ----
    const int i0 = (blockIdx.x + 7 * blockIdx.y) & 31;

    // ---- prologue: stage(i0), bits, K(i0), V(i0) ----
    stage(0, i0 * 64);
    __builtin_amdgcn_sched_barrier(0);
    unsigned long long bcur = brow[i0];
    LOADK(i0 * 64);
    LOADV(i0 * 64);
    __builtin_amdgcn_sched_barrier(0);

#pragma unroll 1
    for (int it = 0; it < 32; ++it) {
        const int p   = it & 1;
        const int i   = (i0 + it) & 31;
        const int in_ = (i + 1) & 31;          // wrap; last prefetch unused
        const int ktn = in_ * 64;

        // ---- 1. QK MFMA (counted K-wait also FIFO-drains stage(i)) ----
        f32x4 sa0 = zero4, sa1 = zero4, sa2 = zero4, sa3 = zero4;
        __builtin_amdgcn_s_setprio(1);
        sa0 = MFMA16(k00, qf0, sa0); sa0 = MFMA16(k01, qf1, sa0);
        sa1 = MFMA16(k10, qf0, sa1); sa1 = MFMA16(k11, qf1, sa1);
        sa2 = MFMA16(k20, qf0, sa2); sa2 = MFMA16(k21, qf1, sa2);
        sa3 = MFMA16(k30, qf0, sa3); sa3 = MFMA16(k31, qf1, sa3);
        __builtin_amdgcn_s_setprio(0);
        __builtin_amdgcn_sched_barrier(0);

        // ---- 2. issue next-iter prefetches: stage, bits, K ----
        stage(p ^ 1, ktn);
        const unsigned long long bnxt = brow[in_];
        LOADK(ktn);
        __builtin_amdgcn_sched_barrier(0);

        // ---- 3. counted drain (stage(i) older than last 30 ops) ----
        asm volatile("s_waitcnt vmcnt(30)" ::: "memory");
        __builtin_amdgcn_sched_barrier(0);

        // ---- 4. W fragments: row r -> quad r>>2, sub-row r&3 ----
        f32x4 wf[4];
        {
            lds_f* wrp = (lds_f*)(&Wlds[p][wv][0]) + (r >> 2)*264 + (r & 3)*64;
            const int jx = 4*(r & 3);
#pragma unroll
            for (int t = 0; t < 4; ++t) {
                lds_f* a = wrp + 4*((4*t + g) ^ jx);
                asm volatile("ds_read_b128 %0, %1" : "=v"(wf[t]) : "v"(a));
            }
        }
        asm volatile("s_waitcnt lgkmcnt(0)" ::: "memory");
        __builtin_amdgcn_sched_barrier(0);

        // ---- 5. logits + online softmax ----
        float lg[16];
        const f32x4 sav[4] = {sa0, sa1, sa2, sa3};
#pragma unroll
        for (int t = 0; t < 4; ++t) {
            const unsigned int half = (t & 2) ? (unsigned int)(bcur >> 32)
                                              : (unsigned int)bcur;
#pragma unroll
            for (int j = 0; j < 4; ++j) {
                const unsigned int bit = (half >> (16*(t & 1) + 4*g + j)) & 1u;
                lg[4*t+j] = bit ? -1e30f : sav[t][j] * wf[t][j];
            }
        }
        float mx = lg[0];
#pragma unroll
        for (int i2 = 1; i2 < 16; ++i2) mx = fmaxf(mx, lg[i2]);
        mx = fmaxf(mx, __shfl_xor(mx, 16, 64));
        mx = fmaxf(mx, __shfl_xor(mx, 32, 64));
        const float mnew = fmaxf(m_run, mx);
        const float fsc  = __expf(m_run - mnew);
        m_run = mnew;
        float p16[16], rs = 0.f;
#pragma unroll
        for (int i2 = 0; i2 < 16; ++i2) { p16[i2] = __expf(lg[i2] - mnew); rs += p16[i2]; }
        rs += __shfl_xor(rs, 16, 64);
        rs += __shfl_xor(rs, 32, 64);
        l_run = l_run * fsc + rs;
        __builtin_amdgcn_sched_barrier(0);

        // ---- 6. P pack + O rescale ----
#pragma unroll
        for (int t = 0; t < 4; ++t) {
            const unsigned int w0 = (unsigned int)f2bf(p16[4*t+0]) |
                                    ((unsigned int)f2bf(p16[4*t+1]) << 16);
            const unsigned int w1 = (unsigned int)f2bf(p16[4*t+2]) |
                                    ((unsigned int)f2bf(p16[4*t+3]) << 16);
            *(int2*)(pbase + roff + ((32*t + 8*g) ^ sw)) = make_int2((int)w0, (int)w1);
        }
        asm volatile("s_waitcnt lgkmcnt(0)" ::: "memory");
        __builtin_amdgcn_sched_barrier(0);
        const bf16x8 pa0 = *(const bf16x8*)(pbase + roff + ((     16*g) ^ sw));
        const bf16x8 pa1 = *(const bf16x8*)(pbase + roff + ((64 + 16*g) ^ sw));
        float fr[4];
#pragma unroll
        for (int j = 0; j < 4; ++j) fr[j] = __shfl(fsc, 4*g + j, 64);
#pragma unroll
        for (int j = 0; j < 4; ++j) {
            oa0[j] *= fr[j]; oa1[j] *= fr[j]; oa2[j] *= fr[j]; oa3[j] *= fr[j];
        }

        // ---- 7. PV (compiler's counted V-wait) ----
        __builtin_amdgcn_s_setprio(1);
        oa0 = MFMA16(pa0, v00, oa0); oa1 = MFMA16(pa0, v01, oa1);
        oa2 = MFMA16(pa0, v02, oa2); oa3 = MFMA16(pa0, v03, oa3);
        oa0 = MFMA16(pa1, v10, oa0); oa1 = MFMA16(pa1, v11, oa1);
        oa2 = MFMA16(pa1, v12, oa2); oa3 = MFMA16(pa1, v13, oa3);
        __builtin_amdgcn_s_setprio(0);
        __builtin_amdgcn_sched_barrier(0);

        // ---- 8. V(next) ----
        LOADV(ktn);
        __builtin_amdgcn_sched_barrier(0);
        bcur = bnxt;
    }
#undef LOADK
#undef LOADV

    // ---- epilogue: normalize + write (b, q, h*64+dv) fp32 ----
    const float inv = 1.0f / l_run;
    float ir[4];
#pragma unroll
    for (int j = 0; j < 4; ++j) ir[j] = __shfl(inv, 4*g + j, 64);
    const int bb = bh >> 3, h = bh & 7;
    const f32x4 oav[4] = {oa0, oa1, oa2, oa3};
#pragma unroll
    for (int nt = 0; nt < 4; ++nt)
#pragma unroll
        for (int j = 0; j < 4; ++j)
            O[((size_t)(bb*NQ_ + q0 + 4*g + j))*DM_ + h*64 + 16*nt + r] = oav[nt][j] * ir[j];
}

// ---------------------------------------------------------------------------
extern "C" void kernel_launch(void* const* d_in, const int* in_sizes, int n_in,
                              void* d_out, int out_size, void* d_ws, size_t ws_size,
                              hipStream_t stream) {
    (void)in_sizes; (void)n_in; (void)out_size; (void)ws_size;

    const float* q    = (const float*)d_in[0];
    const float* k    = (const float*)d_in[1];
    const float* v    = (const float*)d_in[2];
    const float* attw = (const float*)d_in[3];
    const unsigned char* mask = (const unsigned char*)d_in[4];
    const float* Wq = (const float*)d_in[5];
    const float* bq = (const float*)d_in[6];
    const float* Wk = (const float*)d_in[7];
    const float* bk = (const float*)d_in[8];
    const float* Wv = (const float*)d_in[9];
    const float* bv = (const float*)d_in[10];
    const float* Wo = (const float*)d_in[11];
    const float* bo = (const float*)d_in[12];
    float* out = (float*)d_out;

    // ws (shorts): q_bf[NE] k_bf[NE] vT[NE] wt[8*WL] | bits[2Mi u64] | o_ws fp32
    const long long NE = (long long)B_*H_*NQ_*DK_;        // 4Mi
    unsigned short* q_bf = (unsigned short*)d_ws;
    unsigned short* k_bf = q_bf + NE;
    unsigned short* vT   = q_bf + 2*NE;
    unsigned short* wt   = q_bf + 3*NE;
    unsigned long long* bits = (unsigned long long*)(wt + 8LL*WL_);
    const long long NB = (long long)B_*H_*NQ_*NK_/64;     // 2Mi
    float* o_ws = (float*)(bits + NB);

    const dim3 blk(256);
    wprep<<<dim3(8, 8, 4), blk, 0, stream>>>(Wq, Wk, Wv, Wo, wt);
    conv_mask<<<dim3(2048), blk, 0, stream>>>(mask, bits);

    const dim3 gg(128, 8);
    gemm_split<0><<<gg, blk, 0, stream>>>(q, wt + 0*WL_, wt + 1*WL_, bq, q_bf, 0.125f);
    gemm_split<0><<<gg, blk, 0, stream>>>(k, wt + 2*WL_, wt + 3*WL_, bk, k_bf, 1.0f);
    gemm_split<1><<<gg, blk, 0, stream>>>(v, wt + 4*WL_, wt + 5*WL_, bv, vT, 1.0f);

    attn_mfma<<<dim3(NQ_/64, B_*H_), blk, 0, stream>>>(q_bf, k_bf, vT, attw, bits, o_ws);

    gemm_split<2><<<gg, blk, 0, stream>>>(o_ws, wt + 6*WL_, wt + 7*WL_, bo, out, 1.0f);
}

// Round 13
// 395.475 us; speedup vs baseline: 1.7659x; 1.3114x over previous
//
#include <hip/hip_runtime.h>
#include <hip/hip_bf16.h>
#include <math.h>

#define B_   4
#define H_   8
#define NQ_  2048
#define NK_  2048
#define DM_  512
#define DK_  64
#define WL_  262144   // 512*512

typedef short  bf16x8 __attribute__((ext_vector_type(8)));
typedef float  f32x4  __attribute__((ext_vector_type(4)));

static __device__ __forceinline__ f32x4 MFMA16(bf16x8 a, bf16x8 b, f32x4 c) {
    return __builtin_amdgcn_mfma_f32_16x16x32_bf16(a, b, c, 0, 0, 0);
}
static __device__ __forceinline__ unsigned short f2bf(float f) {
    __hip_bfloat16 h = __float2bfloat16(f);
    unsigned short u; __builtin_memcpy(&u, &h, 2); return u;
}
static __device__ __forceinline__ float bf2f(unsigned short u) {
    unsigned int x = ((unsigned int)u) << 16;
    float f; __builtin_memcpy(&f, &x, 4); return f;
}
static __device__ __forceinline__ void glds16(const void* g, void* l) {
    __builtin_amdgcn_global_load_lds(
        (__attribute__((address_space(1))) const void*)g,
        (__attribute__((address_space(3))) void*)l, 16, 0, 0);
}

// ---------------------------------------------------------------------------
// mask -> bitmask, coalesced (lane-contiguous uint4 loads, grid-stride)
// ---------------------------------------------------------------------------
__global__ __launch_bounds__(256) void conv_mask(const unsigned char* __restrict__ Mk,
                                                 unsigned long long* __restrict__ bits)
{
    __shared__ int s_flag;
    const int tid = threadIdx.x;
    if (tid == 0) s_flag = 0;
    __syncthreads();
    {
        bool any = false;
#pragma unroll
        for (int i = 1; i < 16; i += 4)
            if (Mk[tid*16 + i]) any = true;
        if (any) s_flag = 1;
    }
    __syncthreads();

    const long long NELEM = (long long)B_*H_*NQ_*NK_;      // 128Mi
    const long long nth   = (long long)gridDim.x * 256;
    const long long T     = (long long)blockIdx.x * 256 + tid;
    unsigned short* b16   = (unsigned short*)bits;
    const uint4*    src   = (const uint4*)Mk;

    if (s_flag) {
        const long long n = NELEM / 16;
        for (long long t = T; t < n; t += nth) {
            const uint4 u = src[t];
            const unsigned int w[4] = {u.x, u.y, u.z, u.w};
            unsigned int m = 0;
#pragma unroll
            for (int j = 0; j < 4; ++j)
#pragma unroll
                for (int b2 = 0; b2 < 4; ++b2)
                    if ((w[j] >> (8*b2)) & 0xffu) m |= 1u << (4*j + b2);
            b16[t] = (unsigned short)m;
        }
    } else {
        const long long n = NELEM / 4;
        const int l3 = tid & 3;
        for (long long t = T; t < n; t += nth) {
            const uint4 u = src[t];
            const unsigned int nib = (u.x ? 1u : 0u) | (u.y ? 2u : 0u) |
                                     (u.z ? 4u : 0u) | (u.w ? 8u : 0u);
            unsigned int v = nib << (4*l3);
            v |= __shfl_xor(v, 1, 64);
            v |= __shfl_xor(v, 2, 64);
            if (l3 == 0) b16[t >> 2] = (unsigned short)v;
        }
    }
}

// ---------------------------------------------------------------------------
// W (512x512 fp32, [k][n]) -> WT_hi/WT_lo (bf16, [n][k]) for all 4 weights
// ---------------------------------------------------------------------------
__global__ __launch_bounds__(256) void wprep(const float* __restrict__ Wq,
                                             const float* __restrict__ Wk,
                                             const float* __restrict__ Wv,
                                             const float* __restrict__ Wo,
                                             unsigned short* __restrict__ out)
{
    __shared__ float tile[64][65];
    const int tid = threadIdx.x;
    const int k0 = blockIdx.x * 64, n0 = blockIdx.y * 64, w = blockIdx.z;
    const float* W = (w == 0) ? Wq : (w == 1) ? Wk : (w == 2) ? Wv : Wo;
    unsigned short* WTh = out + (size_t)w * 2 * WL_;
    unsigned short* WTl = WTh + WL_;

#pragma unroll
    for (int rd = 0; rd < 4; ++rd) {
        const int k = (tid >> 4) + 16*rd, c4 = (tid & 15) * 4;
        const float4 v4 = *(const float4*)(W + (size_t)(k0 + k)*DM_ + n0 + c4);
        tile[k][c4+0] = v4.x; tile[k][c4+1] = v4.y;
        tile[k][c4+2] = v4.z; tile[k][c4+3] = v4.w;
    }
    __syncthreads();
#pragma unroll
    for (int rd = 0; rd < 4; ++rd) {
        const int n = (tid >> 4) + 16*rd, kk = (tid & 15) * 4;
        unsigned short hh[4], ll[4];
#pragma unroll
        for (int j = 0; j < 4; ++j) {
            const float f = tile[kk + j][n];
            hh[j] = f2bf(f);
            ll[j] = f2bf(f - bf2f(hh[j]));
        }
        *(ushort4*)(WTh + (size_t)(n0 + n)*DM_ + k0 + kk) = make_ushort4(hh[0],hh[1],hh[2],hh[3]);
        *(ushort4*)(WTl + (size_t)(n0 + n)*DM_ + k0 + kk) = make_ushort4(ll[0],ll[1],ll[2],ll[3]);
    }
}

// ---------------------------------------------------------------------------
// Split-bf16 MFMA GEMM: C = A(fp32) @ W + bias (x oscale).
// MODE 0/1: 2-term (Ah*Wh + Ah*Wl) -> bf16 out.  MODE 2: 3-term -> fp32 out.
// ---------------------------------------------------------------------------
template<int MODE>
__global__ __launch_bounds__(256) void gemm_split(
    const float* __restrict__ A,
    const unsigned short* __restrict__ WTh,
    const unsigned short* __restrict__ WTl,
    const float* __restrict__ bias,
    void* __restrict__ outv, const float oscale)
{
    __shared__ unsigned short Ah[64][64], Al[64][64], Bh[64][64], Bl[64][64];

    const int tid = threadIdx.x;
    const int w = tid >> 6, lane = tid & 63, g = lane >> 4, r = lane & 15;
    const int m0 = blockIdx.x * 64, n0 = blockIdx.y * 64;

    char* pAh = (char*)&Ah[0][0];
    char* pAl = (char*)&Al[0][0];
    char* pBh = (char*)&Bh[0][0];
    char* pBl = (char*)&Bl[0][0];

    const f32x4 z4 = {0.f, 0.f, 0.f, 0.f};
    f32x4 acc[4] = {z4, z4, z4, z4};

    for (int kt = 0; kt < DM_; kt += 64) {
#pragma unroll
        for (int rd = 0; rd < 4; ++rd) {
            const int row = (tid >> 4) + 16*rd;
            const int c4  = (tid & 15) * 4;
            const float4 a4 = *(const float4*)(A + (size_t)(m0 + row)*DM_ + kt + c4);
            const float av[4] = {a4.x, a4.y, a4.z, a4.w};
            unsigned short hh[4];
#pragma unroll
            for (int j = 0; j < 4; ++j) hh[j] = f2bf(av[j]);
            const int bo = (c4 * 2) ^ ((row & 7) << 4);
            *(ushort4*)(pAh + row*128 + bo) = make_ushort4(hh[0],hh[1],hh[2],hh[3]);
            if (MODE == 2) {
                unsigned short ll[4];
#pragma unroll
                for (int j = 0; j < 4; ++j) ll[j] = f2bf(av[j] - bf2f(hh[j]));
                *(ushort4*)(pAl + row*128 + bo) = make_ushort4(ll[0],ll[1],ll[2],ll[3]);
            }
        }
#pragma unroll
        for (int rd = 0; rd < 2; ++rd) {
            const int idx = tid + 256*rd;
            const int row = idx >> 3;
            const int cb  = (idx & 7) * 16;
            const int bo  = cb ^ ((row & 7) << 4);
            const size_t goff = (size_t)(n0 + row)*DM_ + kt + (cb >> 1);
            *(bf16x8*)(pBh + row*128 + bo) = *(const bf16x8*)(WTh + goff);
            *(bf16x8*)(pBl + row*128 + bo) = *(const bf16x8*)(WTl + goff);
        }
        __syncthreads();

        const int swr = (r & 7) << 4;
#pragma unroll
        for (int ks = 0; ks < 2; ++ks) {
            const int xo = (64*ks + 16*g) ^ swr;
            const bf16x8 xh = *(const bf16x8*)(pAh + (16*w + r)*128 + xo);
#pragma unroll
            for (int nt = 0; nt < 4; ++nt) {
                const bf16x8 bh = *(const bf16x8*)(pBh + (16*nt + r)*128 + xo);
                const bf16x8 bl = *(const bf16x8*)(pBl + (16*nt + r)*128 + xo);
                if (MODE == 1) {
                    acc[nt] = MFMA16(xh, bh, acc[nt]);
                    acc[nt] = MFMA16(xh, bl, acc[nt]);
                } else if (MODE == 0) {
                    acc[nt] = MFMA16(bh, xh, acc[nt]);
                    acc[nt] = MFMA16(bl, xh, acc[nt]);
                } else {
                    const bf16x8 xl = *(const bf16x8*)(pAl + (16*w + r)*128 + xo);
                    acc[nt] = MFMA16(bh, xh, acc[nt]);
                    acc[nt] = MFMA16(bh, xl, acc[nt]);
                    acc[nt] = MFMA16(bl, xh, acc[nt]);
                }
            }
        }
        __syncthreads();
    }

    if (MODE == 0) {
        const int m = m0 + 16*w + r;
        const int b = m >> 11, q = m & 2047, h = blockIdx.y;
        unsigned short* dst = (unsigned short*)outv + (((size_t)(b*H_ + h))*NQ_ + q)*DK_;
#pragma unroll
        for (int nt = 0; nt < 4; ++nt) {
            unsigned short u[4];
#pragma unroll
            for (int j = 0; j < 4; ++j)
                u[j] = f2bf((acc[nt][j] + bias[n0 + 16*nt + 4*g + j]) * oscale);
            *(ushort4*)(dst + 16*nt + 4*g) = make_ushort4(u[0],u[1],u[2],u[3]);
        }
    } else if (MODE == 1) {
        const int b = m0 >> 11, h = blockIdx.y;
        const int key = (m0 & 2047) + 16*w + 4*g;
#pragma unroll
        for (int nt = 0; nt < 4; ++nt) {
            const int dv = 16*nt + r;
            const float bv = bias[n0 + dv];
            unsigned short u[4];
#pragma unroll
            for (int j = 0; j < 4; ++j) u[j] = f2bf(acc[nt][j] + bv);
            *(ushort4*)((unsigned short*)outv +
                        (((size_t)(b*H_ + h))*DK_ + dv)*NK_ + key) = make_ushort4(u[0],u[1],u[2],u[3]);
        }
    } else {
        const int m = m0 + 16*w + r;
        float* dst = (float*)outv + (size_t)m*DM_ + n0;
#pragma unroll
        for (int nt = 0; nt < 4; ++nt) {
            float4 o4;
            o4.x = acc[nt][0] + bias[n0 + 16*nt + 4*g + 0];
            o4.y = acc[nt][1] + bias[n0 + 16*nt + 4*g + 1];
            o4.z = acc[nt][2] + bias[n0 + 16*nt + 4*g + 2];
            o4.w = acc[nt][3] + bias[n0 + 16*nt + 4*g + 3];
            *(float4*)(dst + 16*nt + 4*g) = o4;
        }
    }
}

// ---------------------------------------------------------------------------
// MFMA flash attention, barrier-synced m97-style staging (NEW this round):
// per 64-key iter the BLOCK stages K(8KB)+V(8KB)+W(16KB) once via glds with
// pre-swizzled sources (read-side XOR matches: 2-way bank-free ds_reads),
// then __syncthreads, compute phase in plain C (compiler-managed waits),
// __syncthreads. 40KB LDS -> 4 blocks/CU fully resident; stall overlap
// across blocks replaces the (compiler-defeated) register pipeline.
// ---------------------------------------------------------------------------
__global__ __launch_bounds__(256, 4) void attn_mfma(
    const unsigned short* __restrict__ Qb,
    const unsigned short* __restrict__ Kb,
    const unsigned short* __restrict__ Vt,
    const float* __restrict__ Wt,
    const unsigned long long* __restrict__ Mb,
    float* __restrict__ O)
{
    __shared__ unsigned short KT[64][64];   // [key][dim] bf16, cg16 ^= key&7
    __shared__ unsigned short VTs[64][64];  // [dv][key]  bf16, cg16 ^= dv&7
    __shared__ float          WT[64][64];   // [q][k]     f32,  cg16 ^= q&15
    __shared__ short          Pl[4][1024];  // P bounce, wave-private 2KB

    const int tid  = threadIdx.x;
    const int wv   = tid >> 6, lane = tid & 63;
    const int g    = lane >> 4, r = lane & 15;
    const int q0   = blockIdx.x * 64 + wv * 16;
    const int bh   = blockIdx.y;

    const size_t kvBase = (size_t)bh * NK_ * DK_;
    const unsigned short* qp = Qb + kvBase + (size_t)(q0 + r)*DK_ + 8*g;
    const bf16x8 qf0 = *(const bf16x8*)qp;
    const bf16x8 qf1 = *(const bf16x8*)(qp + 32);

    const float* wblock = Wt + ((size_t)bh*NQ_ + blockIdx.x*64)*NK_;
    const unsigned long long* brow = Mb + ((size_t)bh*NQ_ + q0 + r)*(NK_/64);
    const unsigned short* kg = Kb + kvBase;            // [key][64]
    const unsigned short* vg = Vt + kvBase;            // [dv][NK]

    const f32x4 zero4 = {0.f, 0.f, 0.f, 0.f};
    f32x4 oa0 = zero4, oa1 = zero4, oa2 = zero4, oa3 = zero4;
    float m_run = -1e30f, l_run = 0.f;

    char* pbase = (char*)&Pl[wv][0];
    const int roff = r * 128;
    const int sw   = (r & 7) << 4;

    // per-lane staging constants
    const int kv_soff = 8 * ((lane & 7) ^ (lane >> 3));   // shorts, swizzled src col
    const int kv_r8   = lane >> 3;                        // row within 8-row chunk
    const int w_r4    = lane >> 4;                        // row within 4-row chunk

#pragma unroll 1
    for (int i = 0; i < 32; ++i) {
        const int kt = i * 64;

        // ---- stage phase: K, V, W via glds (pre-swizzled sources) ----
#pragma unroll
        for (int c = 0; c < 2; ++c) {
            const int rowl = 16*wv + c*8 + kv_r8;         // key / dv row in tile
            glds16(kg + (size_t)(kt + rowl)*DK_ + kv_soff,
                   &KT[16*wv + c*8][0] + lane*8);
            glds16(vg + (size_t)rowl*NK_ + kt + kv_soff,
                   &VTs[16*wv + c*8][0] + lane*8);
        }
#pragma unroll
        for (int c = 0; c < 4; ++c) {
            const int rowl = 16*wv + c*4 + w_r4;          // q row in tile
            glds16(wblock + (size_t)rowl*NK_ + kt + 4*((lane & 15) ^ (c*4 + w_r4)),
                   &WT[16*wv + c*4][0] + lane*4);
        }
        const unsigned long long bcur = brow[i];
        __syncthreads();

        // ---- compute phase (plain C; compiler manages waits) ----
        // K fragments + QK MFMA
        f32x4 sa0 = zero4, sa1 = zero4, sa2 = zero4, sa3 = zero4;
        {
            const bf16x8 k00 = *(const bf16x8*)&KT[ 0 + r][8*((g    ) ^ (r & 7))];
            const bf16x8 k01 = *(const bf16x8*)&KT[ 0 + r][8*((g + 4) ^ (r & 7))];
            const bf16x8 k10 = *(const bf16x8*)&KT[16 + r][8*((g    ) ^ (r & 7))];
            const bf16x8 k11 = *(const bf16x8*)&KT[16 + r][8*((g + 4) ^ (r & 7))];
            const bf16x8 k20 = *(const bf16x8*)&KT[32 + r][8*((g    ) ^ (r & 7))];
            const bf16x8 k21 = *(const bf16x8*)&KT[32 + r][8*((g + 4) ^ (r & 7))];
            const bf16x8 k30 = *(const bf16x8*)&KT[48 + r][8*((g    ) ^ (r & 7))];
            const bf16x8 k31 = *(const bf16x8*)&KT[48 + r][8*((g + 4) ^ (r & 7))];
            sa0 = MFMA16(k00, qf0, sa0); sa0 = MFMA16(k01, qf1, sa0);
            sa1 = MFMA16(k10, qf0, sa1); sa1 = MFMA16(k11, qf1, sa1);
            sa2 = MFMA16(k20, qf0, sa2); sa2 = MFMA16(k21, qf1, sa2);
            sa3 = MFMA16(k30, qf0, sa3); sa3 = MFMA16(k31, qf1, sa3);
        }

        // W fragments
        f32x4 wf[4];
#pragma unroll
        for (int t = 0; t < 4; ++t)
            wf[t] = *(const f32x4*)&WT[16*wv + r][4*((4*t + g) ^ r)];

        // logits + mask
        float lg[16];
        const f32x4 sav[4] = {sa0, sa1, sa2, sa3};
#pragma unroll
        for (int t = 0; t < 4; ++t) {
            const unsigned int half = (t & 2) ? (unsigned int)(bcur >> 32)
                                              : (unsigned int)bcur;
#pragma unroll
            for (int j = 0; j < 4; ++j) {
                const unsigned int bit = (half >> (16*(t & 1) + 4*g + j)) & 1u;
                lg[4*t+j] = bit ? -1e30f : sav[t][j] * wf[t][j];
            }
        }

        // online softmax
        float mx = lg[0];
#pragma unroll
        for (int i2 = 1; i2 < 16; ++i2) mx = fmaxf(mx, lg[i2]);
        mx = fmaxf(mx, __shfl_xor(mx, 16, 64));
        mx = fmaxf(mx, __shfl_xor(mx, 32, 64));
        const float mnew = fmaxf(m_run, mx);
        const float fsc  = __expf(m_run - mnew);
        m_run = mnew;
        float p16[16], rs = 0.f;
#pragma unroll
        for (int i2 = 0; i2 < 16; ++i2) { p16[i2] = __expf(lg[i2] - mnew); rs += p16[i2]; }
        rs += __shfl_xor(rs, 16, 64);
        rs += __shfl_xor(rs, 32, 64);
        l_run = l_run * fsc + rs;

        // P pack -> wave-private LDS -> A-fragments
#pragma unroll
        for (int t = 0; t < 4; ++t) {
            const unsigned int w0 = (unsigned int)f2bf(p16[4*t+0]) |
                                    ((unsigned int)f2bf(p16[4*t+1]) << 16);
            const unsigned int w1 = (unsigned int)f2bf(p16[4*t+2]) |
                                    ((unsigned int)f2bf(p16[4*t+3]) << 16);
            *(int2*)(pbase + roff + ((32*t + 8*g) ^ sw)) = make_int2((int)w0, (int)w1);
        }
        const bf16x8 pa0 = *(const bf16x8*)(pbase + roff + ((     16*g) ^ sw));
        const bf16x8 pa1 = *(const bf16x8*)(pbase + roff + ((64 + 16*g) ^ sw));

        // rescale O
        float fr[4];
#pragma unroll
        for (int j = 0; j < 4; ++j) fr[j] = __shfl(fsc, 4*g + j, 64);
#pragma unroll
        for (int j = 0; j < 4; ++j) {
            oa0[j] *= fr[j]; oa1[j] *= fr[j]; oa2[j] *= fr[j]; oa3[j] *= fr[j];
        }

        // V fragments + PV MFMA
        {
            const bf16x8 v00 = *(const bf16x8*)&VTs[ 0 + r][8*((g    ) ^ (r & 7))];
            const bf16x8 v01 = *(const bf16x8*)&VTs[16 + r][8*((g    ) ^ (r & 7))];
            const bf16x8 v02 = *(const bf16x8*)&VTs[32 + r][8*((g    ) ^ (r & 7))];
            const bf16x8 v03 = *(const bf16x8*)&VTs[48 + r][8*((g    ) ^ (r & 7))];
            const bf16x8 v10 = *(const bf16x8*)&VTs[ 0 + r][8*((g + 4) ^ (r & 7))];
            const bf16x8 v11 = *(const bf16x8*)&VTs[16 + r][8*((g + 4) ^ (r & 7))];
            const bf16x8 v12 = *(const bf16x8*)&VTs[32 + r][8*((g + 4) ^ (r & 7))];
            const bf16x8 v13 = *(const bf16x8*)&VTs[48 + r][8*((g + 4) ^ (r & 7))];
            oa0 = MFMA16(pa0, v00, oa0); oa1 = MFMA16(pa0, v01, oa1);
            oa2 = MFMA16(pa0, v02, oa2); oa3 = MFMA16(pa0, v03, oa3);
            oa0 = MFMA16(pa1, v10, oa0); oa1 = MFMA16(pa1, v11, oa1);
            oa2 = MFMA16(pa1, v12, oa2); oa3 = MFMA16(pa1, v13, oa3);
        }
        __syncthreads();
    }

    // ---- epilogue: normalize + write (b, q, h*64+dv) fp32 ----
    const float inv = 1.0f / l_run;
    float ir[4];
#pragma unroll
    for (int j = 0; j < 4; ++j) ir[j] = __shfl(inv, 4*g + j, 64);
    const int bb = bh >> 3, h = bh & 7;
    const f32x4 oav[4] = {oa0, oa1, oa2, oa3};
#pragma unroll
    for (int nt = 0; nt < 4; ++nt)
#pragma unroll
        for (int j = 0; j < 4; ++j)
            O[((size_t)(bb*NQ_ + q0 + 4*g + j))*DM_ + h*64 + 16*nt + r] = oav[nt][j] * ir[j];
}

// ---------------------------------------------------------------------------
extern "C" void kernel_launch(void* const* d_in, const int* in_sizes, int n_in,
                              void* d_out, int out_size, void* d_ws, size_t ws_size,
                              hipStream_t stream) {
    (void)in_sizes; (void)n_in; (void)out_size; (void)ws_size;

    const float* q    = (const float*)d_in[0];
    const float* k    = (const float*)d_in[1];
    const float* v    = (const float*)d_in[2];
    const float* attw = (const float*)d_in[3];
    const unsigned char* mask = (const unsigned char*)d_in[4];
    const float* Wq = (const float*)d_in[5];
    const float* bq = (const float*)d_in[6];
    const float* Wk = (const float*)d_in[7];
    const float* bk = (const float*)d_in[8];
    const float* Wv = (const float*)d_in[9];
    const float* bv = (const float*)d_in[10];
    const float* Wo = (const float*)d_in[11];
    const float* bo = (const float*)d_in[12];
    float* out = (float*)d_out;

    // ws (shorts): q_bf[NE] k_bf[NE] vT[NE] wt[8*WL] | bits[2Mi u64] | o_ws fp32
    const long long NE = (long long)B_*H_*NQ_*DK_;        // 4Mi
    unsigned short* q_bf = (unsigned short*)d_ws;
    unsigned short* k_bf = q_bf + NE;
    unsigned short* vT   = q_bf + 2*NE;
    unsigned short* wt   = q_bf + 3*NE;
    unsigned long long* bits = (unsigned long long*)(wt + 8LL*WL_);
    const long long NB = (long long)B_*H_*NQ_*NK_/64;     // 2Mi
    float* o_ws = (float*)(bits + NB);

    const dim3 blk(256);
    wprep<<<dim3(8, 8, 4), blk, 0, stream>>>(Wq, Wk, Wv, Wo, wt);
    conv_mask<<<dim3(2048), blk, 0, stream>>>(mask, bits);

    const dim3 gg(128, 8);
    gemm_split<0><<<gg, blk, 0, stream>>>(q, wt + 0*WL_, wt + 1*WL_, bq, q_bf, 0.125f);
    gemm_split<0><<<gg, blk, 0, stream>>>(k, wt + 2*WL_, wt + 3*WL_, bk, k_bf, 1.0f);
    gemm_split<1><<<gg, blk, 0, stream>>>(v, wt + 4*WL_, wt + 5*WL_, bv, vT, 1.0f);

    attn_mfma<<<dim3(NQ_/64, B_*H_), blk, 0, stream>>>(q_bf, k_bf, vT, attw, bits, o_ws);

    gemm_split<2><<<gg, blk, 0, stream>>>(o_ws, wt + 6*WL_, wt + 7*WL_, bo, out, 1.0f);
}